// Round 5
// baseline (698.466 us; speedup 1.0000x reference)
//
#include <hip/hip_runtime.h>
#include <math.h>

// ---------- problem constants ----------
// B=16, F=256, C=64, H=64, W=64, N_E=512. Inputs fp32, outputs fp32.
// tokens: rows r=(b*64+c)*64+h of 64 w-values; 65536 tokens total.
// fp32 main pass; tokens with top-2 gap < MARGIN re-resolved in fp64.

#define CAP    2048
#define MARGIN 4e-3f

// ---------- workspace layout (float offsets; doubles at even offsets) ----------
#define WS_WT   0        // [16384]   W' float [f][o]
#define WS_BP   16384    // [64]      fused bias float
#define WS_EN   16448    // [512]     code norms
#define WS_E2   16960    // [512]     code sq-norms
#define WS_ACC  17472    // [8]       accumulators: 0=mse 1=var 2=tmd
#define WS_CNT  17480    // [8]       int counter region
#define WS_WL   17488    // [2048]    int worklist
#define WS_EFT  19536    // [64*512]  embedding transposed float [k][n]
#define WS_AD   52304    // [256 dbl] bn scale a_f
#define WS_CD   52816    // [256 dbl] bn shift c_f
#define WS_WD   53328    // [16384 dbl] W' double [o][f]  (aliased: bn partials before prep_w)
#define WS_BPD  86096    // [64 dbl]  fused bias double
// total 86224 floats = 345 KB (<= round-4's 355 KB usage)

// ============================================================
// K1a: BN partial sums (fp64). grid 1024 = f*4 + chunk; chunk = 4 batches.
// ============================================================
__global__ __launch_bounds__(256) void bn_partial(
    const float* __restrict__ x, double* __restrict__ part)
{
    const int f = blockIdx.x >> 2, ch = blockIdx.x & 3, t = threadIdx.x;
    double s = 0.0, q = 0.0;
    #pragma unroll
    for (int bb = 0; bb < 4; ++bb) {
        const int b = ch * 4 + bb;
        const float4* p = (const float4*)(x + ((size_t)(b * 256 + f) << 12));
        #pragma unroll
        for (int ii = 0; ii < 4; ++ii) {
            float4 u = p[t + ii * 256];
            double dx = u.x, dy = u.y, dz = u.z, dw = u.w;
            s += (dx + dy) + (dz + dw);
            q = fma(dx, dx, q); q = fma(dy, dy, q);
            q = fma(dz, dz, q); q = fma(dw, dw, q);
        }
    }
    #pragma unroll
    for (int off = 32; off; off >>= 1) { s += __shfl_xor(s, off, 64); q += __shfl_xor(q, off, 64); }
    __shared__ double sh[8];
    const int wv = t >> 6;
    if ((t & 63) == 0) { sh[wv * 2] = s; sh[wv * 2 + 1] = q; }
    __syncthreads();
    if (t == 0) {
        part[blockIdx.x * 2]     = (sh[0] + sh[2]) + (sh[4] + sh[6]);
        part[blockIdx.x * 2 + 1] = (sh[1] + sh[3]) + (sh[5] + sh[7]);
    }
}

// ============================================================
// K1b: finalize BN -> a_f, c_f (fp64)
// ============================================================
__global__ __launch_bounds__(256) void bn_final(
    const double* __restrict__ part,
    const float* __restrict__ gamma, const float* __restrict__ beta,
    double* __restrict__ ad, double* __restrict__ cd)
{
    const int f = threadIdx.x;
    double s = 0.0, q = 0.0;
    #pragma unroll
    for (int c = 0; c < 4; ++c) { s += part[(f * 4 + c) * 2]; q += part[(f * 4 + c) * 2 + 1]; }
    double mean = s * (1.0 / 65536.0);
    double var  = q * (1.0 / 65536.0) - mean * mean;
    double a = (double)gamma[f] / sqrt(var + 1e-5);
    ad[f] = a;
    cd[f] = (double)beta[f] - mean * a;
}

// ============================================================
// K2a: W' fold (fp64) + embedding transpose/norms. 64 blocks x 256.
// ============================================================
__global__ __launch_bounds__(256) void prep_w(
    const float* __restrict__ w1,   // [64][256]
    const float* __restrict__ w2,   // [64][64]
    const double* __restrict__ ad,
    const float* __restrict__ emb,  // [512][64]
    float* __restrict__ Wt,         // float [f][o]
    double* __restrict__ Wd,        // double [o][f]
    float* __restrict__ eft, float* __restrict__ en, float* __restrict__ e2)
{
    const int t = threadIdx.x;
    const int o = t & 63, fi = t >> 6;
    const int f = blockIdx.x * 4 + fi;
    double s = 0.0;
    for (int c = 0; c < 64; ++c)
        s = fma((double)w2[o * 64 + c], (double)w1[c * 256 + f], s);
    double wp = s * ad[f];
    Wd[o * 256 + f] = wp;
    Wt[f * 64 + o]  = (float)wp;

    // embedding rows for this block: n in [blk*8, blk*8+8); wave wv covers 2 rows
    const int lane = t & 63, wv = t >> 6;
    #pragma unroll
    for (int rr = 0; rr < 2; ++rr) {
        int n = blockIdx.x * 8 + rr * 4 + wv;
        float v = emb[n * 64 + lane];
        eft[lane * 512 + n] = v;
        float qq = v * v;
        #pragma unroll
        for (int off = 32; off; off >>= 1) qq += __shfl_xor(qq, off, 64);
        if (lane == 0) { e2[n] = qq; en[n] = sqrtf(qq); }
    }
}

// ============================================================
// K2b: fp64 fused bias b'; zero accs/counter. 1 block x 256.
// ============================================================
__global__ __launch_bounds__(256) void prep_bias(
    const float* __restrict__ w1,
    const float* __restrict__ w2,
    const float* __restrict__ b1,
    const float* __restrict__ b2,
    const double* __restrict__ cd,
    float* __restrict__ bp, double* __restrict__ bpd,
    float* __restrict__ accs, int* __restrict__ cnt)
{
    __shared__ double red[4][64];
    __shared__ double tsh[64];
    const int t = threadIdx.x;
    const int o = t & 63, p = t >> 6;
    double s = 0.0;
    for (int j = 0; j < 64; ++j) {
        int fidx = p * 64 + j;
        s = fma((double)w1[o * 256 + fidx], cd[fidx], s);
    }
    red[p][o] = s; __syncthreads();
    if (t < 64) tsh[t] = (double)b1[t] + (red[0][t] + red[1][t]) + (red[2][t] + red[3][t]);
    __syncthreads();
    if (t < 64) {
        double bb = (double)b2[t];
        for (int c = 0; c < 64; ++c)
            bb = fma((double)w2[t * 64 + c], tsh[c], bb);
        bpd[t] = bb;
        bp[t]  = (float)bb;
    }
    if (t < 8) accs[t] = 0.f;
    if (t == 0) cnt[0] = 0;
}

// ============================================================
// K3: fused GEMM + VQ. Block = 4 waves per (b,h).
// GEMM: wave wv accumulates features [wv*64,(wv+1)*64) (K-split, direct loads).
// VQ:   wave wv scans codes [wv*128,(wv+1)*128); top-2 merged in LDS.
// ============================================================
__global__ __launch_bounds__(256, 4) void fused_gemm_vq(
    const float* __restrict__ x,
    const float* __restrict__ Wt,      // [256 f][64 o]
    const float* __restrict__ bp,      // [64]
    const float* __restrict__ emb,     // [512][64] fp32
    const float* __restrict__ e2,      // [512]
    float* __restrict__ accs,
    int* __restrict__ cnt, int* __restrict__ wl,
    float* __restrict__ zq)            // = out+1, fp32
{
    __shared__ float zsA[64 * 65];
    __shared__ float zsB[64 * 65];
    __shared__ float dA[4][64];
    __shared__ float d2A[4][64];
    __shared__ int   iA[4][64];

    const int tid = threadIdx.x, lane = tid & 63, wv = tid >> 6;
    const int b = blockIdx.x >> 6;
    const int h = blockIdx.x & 63;

    float acc[64];
    #pragma unroll
    for (int c = 0; c < 64; ++c) acc[c] = 0.f;

    const float* xb = x + ((size_t)(b * 256 + wv * 64) << 12) + (h << 6) + lane;
    const float* wp = Wt + (wv * 64) * 64;
    #pragma unroll 4
    for (int i = 0; i < 64; ++i) {
        float xv = xb[(size_t)i << 12];
        #pragma unroll
        for (int c = 0; c < 64; ++c)
            acc[c] = fmaf(wp[i * 64 + c], xv, acc[c]);   // wp uniform -> s_load
    }

    // tree-reduce partials: (0,+2) -> zsA, (1,+3) -> zsB, then zsA += zsB
    if (wv == 0) {
        #pragma unroll
        for (int c = 0; c < 64; ++c) zsA[c * 65 + lane] = acc[c] + bp[c];
    } else if (wv == 1) {
        #pragma unroll
        for (int c = 0; c < 64; ++c) zsB[c * 65 + lane] = acc[c];
    }
    __syncthreads();
    if (wv == 2) {
        #pragma unroll
        for (int c = 0; c < 64; ++c) zsA[c * 65 + lane] += acc[c];
    } else if (wv == 3) {
        #pragma unroll
        for (int c = 0; c < 64; ++c) zsB[c * 65 + lane] += acc[c];
    }
    __syncthreads();
    #pragma unroll
    for (int cc = 0; cc < 16; ++cc) {
        int c = wv * 16 + cc;
        zsA[c * 65 + lane] += zsB[c * 65 + lane];
    }
    __syncthreads();

    // VQ: lane = token (channel c=lane); this wave scans 128 codes
    float zr[64];
    #pragma unroll
    for (int k = 0; k < 64; ++k) zr[k] = zsA[lane * 65 + k];
    float z2 = 0.f;
    #pragma unroll
    for (int k = 0; k < 64; ++k) z2 = fmaf(zr[k], zr[k], z2);

    float dmin = 3.4e38f, d2nd = 3.4e38f;
    int bidx = 0;
    const int n0 = wv << 7;
    #pragma unroll 1
    for (int nn = 0; nn < 128; ++nn) {
        const int n = n0 + nn;
        const float* ep = emb + (n << 6);                // uniform -> s_load
        float d0 = 0.f, d1 = 0.f, d2 = 0.f, d3 = 0.f;
        #pragma unroll
        for (int k = 0; k < 64; k += 4) {
            d0 = fmaf(zr[k + 0], ep[k + 0], d0);
            d1 = fmaf(zr[k + 1], ep[k + 1], d1);
            d2 = fmaf(zr[k + 2], ep[k + 2], d2);
            d3 = fmaf(zr[k + 3], ep[k + 3], d3);
        }
        float dot = (d0 + d1) + (d2 + d3);
        float d = z2 + e2[n] - 2.f * dot;
        if (d < dmin)      { d2nd = dmin; dmin = d; bidx = n; }
        else if (d < d2nd) { d2nd = d; }
    }
    dA[wv][lane] = dmin; d2A[wv][lane] = d2nd; iA[wv][lane] = bidx;
    __syncthreads();

    if (wv == 0) {
        float m1 = dA[0][lane], m2 = d2A[0][lane];
        int bi = iA[0][lane];
        #pragma unroll
        for (int p = 1; p < 4; ++p) {
            float a1 = dA[p][lane], a2 = d2A[p][lane]; int ai = iA[p][lane];
            if (a1 < m1) { m2 = fminf(m1, a2); m1 = a1; bi = ai; }
            else         { m2 = fminf(m2, a1); }       // a2 >= a1, so a1 suffices
        }
        iA[0][lane] = bi;                               // publish merged idx
        if (m2 - m1 < MARGIN) {                         // near-tie -> fp64 refine
            int pos = atomicAdd(cnt, 1);
            if (pos < CAP) wl[pos] = ((b << 6) + lane) * 64 + h;
        }
        float ms = m1;
        #pragma unroll
        for (int off = 32; off; off >>= 1) ms += __shfl_xor(ms, off, 64);
        if (lane == 0) atomicAdd(accs + 0, ms);
    }
    __syncthreads();

    // z_q write: wave wv writes channels [wv*16,(wv+1)*16), coalesced over lanes
    float* zrow = zq + ((size_t)(b * 64) << 12) + (h << 6) + lane;
    #pragma unroll 1
    for (int cc = 0; cc < 16; ++cc) {
        int c = wv * 16 + cc;
        int id = iA[0][c];                              // LDS broadcast
        zrow[(size_t)c << 12] = emb[(id << 6) + lane];
    }
}

// ============================================================
// K3b: fp64 refinement of flagged tokens (persistent grid-stride)
// ============================================================
__global__ __launch_bounds__(256) void refine(
    const float* __restrict__ x,
    const double* __restrict__ Wd,     // [o][f] double
    const double* __restrict__ bpd,    // [64] double
    const float* __restrict__ emb,     // [512][64]
    const float* __restrict__ eft,     // [64][512]
    const int* __restrict__ cnt, const int* __restrict__ wl,
    float* __restrict__ zq)
{
    int count = cnt[0]; if (count > CAP) count = CAP;
    const int tid = threadIdx.x, lane = tid & 63, wv = tid >> 6;

    __shared__ double zp[4][64];
    __shared__ double zs[64];
    __shared__ double dsh[256];
    __shared__ int    ish[256];

    for (int it = blockIdx.x; it < count; it += gridDim.x) {
        const int r = wl[it];
        const int b = r >> 12, c = (r >> 6) & 63, h = r & 63;

        const float* xp = x + (((size_t)(b * 256 + wv * 64)) << 12) + (h << 6) + lane;
        const double* wrow = Wd + c * 256 + wv * 64;
        double zd = 0.0;
        #pragma unroll 8
        for (int f = 0; f < 64; ++f)
            zd = fma(wrow[f], (double)xp[((size_t)f) << 12], zd);
        zp[wv][lane] = zd;
        __syncthreads();
        if (tid < 64) zs[tid] = (zp[0][tid] + zp[1][tid]) + (zp[2][tid] + zp[3][tid]) + bpd[c];
        __syncthreads();

        double dm = 1e300; int im = 0;
        #pragma unroll
        for (int jj = 0; jj < 2; ++jj) {
            int n = (jj << 8) + tid;
            double d = 0.0;
            #pragma unroll 8
            for (int k = 0; k < 64; ++k) {
                double t = zs[k] - (double)eft[(k << 9) + n];
                d = fma(t, t, d);
            }
            if (d < dm) { dm = d; im = n; }
        }
        dsh[tid] = dm; ish[tid] = im;
        __syncthreads();
        for (int st = 128; st; st >>= 1) {
            if (tid < st) {
                double od = dsh[tid + st]; int oi = ish[tid + st];
                if (od < dsh[tid] || (od == dsh[tid] && oi < ish[tid])) { dsh[tid] = od; ish[tid] = oi; }
            }
            __syncthreads();
        }
        if (tid < 64) {
            int idx = ish[0];
            zq[((size_t)r << 6) + tid] = emb[(idx << 6) + tid];
        }
        __syncthreads();
    }
}

// ============================================================
// K4: codebook angular stats (symmetric: col 2nd-min == row 2nd-min)
// ============================================================
__global__ __launch_bounds__(64) void cb_stats(
    const float* __restrict__ emb, const float* __restrict__ eft,
    const float* __restrict__ en, float* __restrict__ accs)
{
    __shared__ float ang[512];
    const int lane = threadIdx.x;
    const int i = blockIdx.x;
    const float eni = en[i];
    const float* ei = emb + (i << 6);    // uniform
    float m1 = 3.4e38f, m2 = 3.4e38f, ssum = 0.f;
    #pragma unroll 1
    for (int jj = 0; jj < 8; ++jj) {
        int j = (jj << 6) + lane;
        float d0 = 0.f, d1 = 0.f, d2 = 0.f, d3 = 0.f;
        #pragma unroll
        for (int k = 0; k < 64; k += 4) {
            d0 = fmaf(ei[k + 0], eft[(k + 0) * 512 + j], d0);
            d1 = fmaf(ei[k + 1], eft[(k + 1) * 512 + j], d1);
            d2 = fmaf(ei[k + 2], eft[(k + 2) * 512 + j], d2);
            d3 = fmaf(ei[k + 3], eft[(k + 3) * 512 + j], d3);
        }
        float dot = (d0 + d1) + (d2 + d3);
        float xv = dot / (eni * en[j]);
        xv = fminf(fmaxf(xv, -0.99999f), 0.99999f);
        float a = acosf(xv);
        ang[j] = a;
        ssum += a;
        if (a < m1) { m2 = m1; m1 = a; }
        else if (a < m2) m2 = a;
    }
    __syncthreads();
    #pragma unroll
    for (int off = 32; off; off >>= 1) ssum += __shfl_xor(ssum, off, 64);
    #pragma unroll
    for (int off = 32; off; off >>= 1) {
        float o1 = __shfl_xor(m1, off, 64);
        float o2 = __shfl_xor(m2, off, 64);
        if (o1 < m1) { m2 = fminf(m1, o2); m1 = o1; }
        else          m2 = fminf(m2, o1);
    }
    float mean = ssum * (1.f / 512.f);
    float vs = 0.f;
    #pragma unroll
    for (int jj = 0; jj < 8; ++jj) {
        float t = ang[(jj << 6) + lane] - mean;
        vs = fmaf(t, t, vs);
    }
    #pragma unroll
    for (int off = 32; off; off >>= 1) vs += __shfl_xor(vs, off, 64);
    if (lane == 0) {
        atomicAdd(accs + 1, vs * (1.f / 511.f));  // row variance (ddof=1)
        atomicAdd(accs + 2, m2);                  // row second-smallest
    }
}

// ============================================================
// K5: finalize scalars (fp32 out)
// ============================================================
__global__ __launch_bounds__(64) void finalize(
    const float* __restrict__ accs, const float* __restrict__ en,
    const float* __restrict__ r, float* __restrict__ out)
{
    const int lane = threadIdx.x;
    float hs = 0.f, rs = 0.f;
    #pragma unroll
    for (int jj = 0; jj < 8; ++jj) {
        int n = (jj << 6) + lane;
        float rv = r[n];
        float d = rv - en[n];
        hs = fmaf(d, d, hs);
        rs += fminf(fmaxf(rv, 0.9f), 1.1f);
    }
    #pragma unroll
    for (int off = 32; off; off >>= 1) { hs += __shfl_xor(hs, off, 64); rs += __shfl_xor(rs, off, 64); }
    if (lane == 0) {
        float hsw    = hs * (1.f / 512.f);
        float mean_r = rs * (1.f / 512.f);
        float mse    = accs[0] * (1.f / 4194304.f);
        float cbv    = accs[1] * (1.f / 512.f);
        float tmd    = accs[2] * (1.f / 512.f);
        float loss   = 2.f * mse + hsw + (cbv - tmd);   // beta=1 -> both commit terms equal
        out[0]       = loss;
        out[4194305] = cbv;
        out[4194306] = tmd;
        out[4194307] = hsw;
        out[4194308] = 0.f;                             // cb_loss = 0
        out[4194309] = mean_r;
    }
}

// ============================================================
extern "C" void kernel_launch(void* const* d_in, const int* in_sizes, int n_in,
                              void* d_out, int out_size, void* d_ws, size_t ws_size,
                              hipStream_t stream) {
    const float* x   = (const float*)d_in[0];
    const float* g1  = (const float*)d_in[1];
    const float* be1 = (const float*)d_in[2];
    const float* w1  = (const float*)d_in[3];
    const float* b1  = (const float*)d_in[4];
    const float* w2  = (const float*)d_in[5];
    const float* b2  = (const float*)d_in[6];
    const float* emb = (const float*)d_in[7];
    const float* r   = (const float*)d_in[8];
    float* ws = (float*)d_ws;
    float* out = (float*)d_out;

    double* AD   = (double*)(ws + WS_AD);
    double* CD   = (double*)(ws + WS_CD);
    double* WD   = (double*)(ws + WS_WD);
    double* PART = (double*)(ws + WS_WD);   // aliased: consumed before WD written
    double* BPD  = (double*)(ws + WS_BPD);
    int*    CNT  = (int*)(ws + WS_CNT);
    int*    WL   = (int*)(ws + WS_WL);

    bn_partial<<<1024, 256, 0, stream>>>(x, PART);
    bn_final<<<1, 256, 0, stream>>>(PART, g1, be1, AD, CD);
    prep_w<<<64, 256, 0, stream>>>(w1, w2, AD, emb, ws + WS_WT, WD,
                                   ws + WS_EFT, ws + WS_EN, ws + WS_E2);
    prep_bias<<<1, 256, 0, stream>>>(w1, w2, b1, b2, CD,
                                     ws + WS_BP, BPD, ws + WS_ACC, CNT);
    fused_gemm_vq<<<1024, 256, 0, stream>>>(x, ws + WS_WT, ws + WS_BP,
                                            emb, ws + WS_E2, ws + WS_ACC,
                                            CNT, WL, out + 1);
    refine<<<256, 256, 0, stream>>>(x, WD, BPD, emb, ws + WS_EFT, CNT, WL, out + 1);
    cb_stats<<<512, 64, 0, stream>>>(emb, ws + WS_EFT, ws + WS_EN, ws + WS_ACC);
    finalize<<<1, 64, 0, stream>>>(ws + WS_ACC, ws + WS_EN, r, out);
}

// Round 6
// 541.937 us; speedup vs baseline: 1.2888x; 1.2888x over previous
//
#include <hip/hip_runtime.h>
#include <math.h>

// ---------- problem constants ----------
// B=16, F=256, C=64, H=64, W=64, N_E=512. Inputs fp32, outputs fp32.
// tokens: rows r=(b*64+c)*64+h of 64 w-values; 65536 tokens total.
// fp32 main pass; tokens with top-2 gap < MARGIN re-resolved in fp64.

#define CAP    2048
#define MARGIN 4e-3f

// ---------- workspace layout (float offsets; doubles at even offsets) ----------
#define WS_WT   0        // [16384]   W' float [f][o]
#define WS_BP   16384    // [64]      fused bias float
#define WS_EN   16448    // [512]     code norms
#define WS_E2   16960    // [512]     code sq-norms
#define WS_ACC  17472    // [8]       accumulators: 0=mse 1=var 2=tmd
#define WS_CNT  17480    // [8]       int counter region
#define WS_WL   17488    // [2048]    int worklist
#define WS_EFT  19536    // [64*512]  embedding transposed float [k][n]
#define WS_AD   52304    // [256 dbl] bn scale a_f
#define WS_CD   52816    // [256 dbl] bn shift c_f
#define WS_WD   53328    // [16384 dbl] W' double [o][f]  (aliased: bn partials before prep_w)
#define WS_BPD  86096    // [64 dbl]  fused bias double

// ============================================================
// K1a: BN partial sums (fp64). grid 1024 = f*4 + chunk; chunk = 4 batches.
// ============================================================
__global__ __launch_bounds__(256) void bn_partial(
    const float* __restrict__ x, double* __restrict__ part)
{
    const int f = blockIdx.x >> 2, ch = blockIdx.x & 3, t = threadIdx.x;
    double s = 0.0, q = 0.0;
    #pragma unroll
    for (int bb = 0; bb < 4; ++bb) {
        const int b = ch * 4 + bb;
        const float4* p = (const float4*)(x + ((size_t)(b * 256 + f) << 12));
        #pragma unroll
        for (int ii = 0; ii < 4; ++ii) {
            float4 u = p[t + ii * 256];
            double dx = u.x, dy = u.y, dz = u.z, dw = u.w;
            s += (dx + dy) + (dz + dw);
            q = fma(dx, dx, q); q = fma(dy, dy, q);
            q = fma(dz, dz, q); q = fma(dw, dw, q);
        }
    }
    #pragma unroll
    for (int off = 32; off; off >>= 1) { s += __shfl_xor(s, off, 64); q += __shfl_xor(q, off, 64); }
    __shared__ double sh[8];
    const int wv = t >> 6;
    if ((t & 63) == 0) { sh[wv * 2] = s; sh[wv * 2 + 1] = q; }
    __syncthreads();
    if (t == 0) {
        part[blockIdx.x * 2]     = (sh[0] + sh[2]) + (sh[4] + sh[6]);
        part[blockIdx.x * 2 + 1] = (sh[1] + sh[3]) + (sh[5] + sh[7]);
    }
}

// ============================================================
// K1b: finalize BN -> a_f, c_f (fp64)
// ============================================================
__global__ __launch_bounds__(256) void bn_final(
    const double* __restrict__ part,
    const float* __restrict__ gamma, const float* __restrict__ beta,
    double* __restrict__ ad, double* __restrict__ cd)
{
    const int f = threadIdx.x;
    double s = 0.0, q = 0.0;
    #pragma unroll
    for (int c = 0; c < 4; ++c) { s += part[(f * 4 + c) * 2]; q += part[(f * 4 + c) * 2 + 1]; }
    double mean = s * (1.0 / 65536.0);
    double var  = q * (1.0 / 65536.0) - mean * mean;
    double a = (double)gamma[f] / sqrt(var + 1e-5);
    ad[f] = a;
    cd[f] = (double)beta[f] - mean * a;
}

// ============================================================
// K2a: W' fold (fp64) + embedding transpose/norms. 64 blocks x 256.
// ============================================================
__global__ __launch_bounds__(256) void prep_w(
    const float* __restrict__ w1,   // [64][256]
    const float* __restrict__ w2,   // [64][64]
    const double* __restrict__ ad,
    const float* __restrict__ emb,  // [512][64]
    float* __restrict__ Wt,         // float [f][o]
    double* __restrict__ Wd,        // double [o][f]
    float* __restrict__ eft, float* __restrict__ en, float* __restrict__ e2)
{
    const int t = threadIdx.x;
    const int o = t & 63, fi = t >> 6;
    const int f = blockIdx.x * 4 + fi;
    double s = 0.0;
    for (int c = 0; c < 64; ++c)
        s = fma((double)w2[o * 64 + c], (double)w1[c * 256 + f], s);
    double wp = s * ad[f];
    Wd[o * 256 + f] = wp;
    Wt[f * 64 + o]  = (float)wp;

    // embedding rows for this block: n in [blk*8, blk*8+8); wave wv covers 2 rows
    const int lane = t & 63, wv = t >> 6;
    #pragma unroll
    for (int rr = 0; rr < 2; ++rr) {
        int n = blockIdx.x * 8 + rr * 4 + wv;
        float v = emb[n * 64 + lane];
        eft[lane * 512 + n] = v;
        float qq = v * v;
        #pragma unroll
        for (int off = 32; off; off >>= 1) qq += __shfl_xor(qq, off, 64);
        if (lane == 0) { e2[n] = qq; en[n] = sqrtf(qq); }
    }
}

// ============================================================
// K2b: fp64 fused bias b'; zero accs/counter. 1 block x 256.
// ============================================================
__global__ __launch_bounds__(256) void prep_bias(
    const float* __restrict__ w1,
    const float* __restrict__ w2,
    const float* __restrict__ b1,
    const float* __restrict__ b2,
    const double* __restrict__ cd,
    float* __restrict__ bp, double* __restrict__ bpd,
    float* __restrict__ accs, int* __restrict__ cnt)
{
    __shared__ double red[4][64];
    __shared__ double tsh[64];
    const int t = threadIdx.x;
    const int o = t & 63, p = t >> 6;
    double s = 0.0;
    for (int j = 0; j < 64; ++j) {
        int fidx = p * 64 + j;
        s = fma((double)w1[o * 256 + fidx], cd[fidx], s);
    }
    red[p][o] = s; __syncthreads();
    if (t < 64) tsh[t] = (double)b1[t] + (red[0][t] + red[1][t]) + (red[2][t] + red[3][t]);
    __syncthreads();
    if (t < 64) {
        double bb = (double)b2[t];
        for (int c = 0; c < 64; ++c)
            bb = fma((double)w2[t * 64 + c], tsh[c], bb);
        bpd[t] = bb;
        bp[t]  = (float)bb;
    }
    if (t < 8) accs[t] = 0.f;
    if (t == 0) cnt[0] = 0;
}

// ============================================================
// K3: fused GEMM + VQ. Block = 4 waves per (b,h).
// GEMM: wave wv accumulates features [wv*64,(wv+1)*64) (K-split, direct loads).
// VQ:   wave wv scans codes [wv*128,(wv+1)*128); top-2 merged in LDS.
// __launch_bounds__(256,2): VGPR cap 256 -> NO SPILL (256,4 capped at 128 and
// spilled acc[64] to scratch: 499 MB WRITE_SIZE, 558 us. Round-5 lesson.)
// ============================================================
__global__ __launch_bounds__(256, 2) void fused_gemm_vq(
    const float* __restrict__ x,
    const float* __restrict__ Wt,      // [256 f][64 o]
    const float* __restrict__ bp,      // [64]
    const float* __restrict__ emb,     // [512][64] fp32
    const float* __restrict__ e2,      // [512]
    float* __restrict__ accs,
    int* __restrict__ cnt, int* __restrict__ wl,
    float* __restrict__ zq)            // = out+1, fp32
{
    __shared__ float zsA[64 * 65];
    __shared__ float zsB[64 * 65];
    __shared__ float dA[4][64];
    __shared__ float d2A[4][64];
    __shared__ int   iA[4][64];

    const int tid = threadIdx.x, lane = tid & 63, wv = tid >> 6;
    const int b = blockIdx.x >> 6;
    const int h = blockIdx.x & 63;

    float acc[64];
    #pragma unroll
    for (int c = 0; c < 64; ++c) acc[c] = 0.f;

    const float* xb = x + ((size_t)(b * 256 + wv * 64) << 12) + (h << 6) + lane;
    const float* wp = Wt + (wv * 64) * 64;
    #pragma unroll 4
    for (int i = 0; i < 64; ++i) {
        float xv = xb[(size_t)i << 12];
        #pragma unroll
        for (int c = 0; c < 64; ++c)
            acc[c] = fmaf(wp[i * 64 + c], xv, acc[c]);   // wp uniform -> s_load
    }

    // tree-reduce partials: (0,+2) -> zsA, (1,+3) -> zsB, then zsA += zsB
    if (wv == 0) {
        #pragma unroll
        for (int c = 0; c < 64; ++c) zsA[c * 65 + lane] = acc[c] + bp[c];
    } else if (wv == 1) {
        #pragma unroll
        for (int c = 0; c < 64; ++c) zsB[c * 65 + lane] = acc[c];
    }
    __syncthreads();
    if (wv == 2) {
        #pragma unroll
        for (int c = 0; c < 64; ++c) zsA[c * 65 + lane] += acc[c];
    } else if (wv == 3) {
        #pragma unroll
        for (int c = 0; c < 64; ++c) zsB[c * 65 + lane] += acc[c];
    }
    __syncthreads();
    #pragma unroll
    for (int cc = 0; cc < 16; ++cc) {
        int c = wv * 16 + cc;
        zsA[c * 65 + lane] += zsB[c * 65 + lane];
    }
    __syncthreads();

    // VQ: lane = token (channel c=lane); this wave scans 128 codes
    float zr[64];
    #pragma unroll
    for (int k = 0; k < 64; ++k) zr[k] = zsA[lane * 65 + k];
    float z2 = 0.f;
    #pragma unroll
    for (int k = 0; k < 64; ++k) z2 = fmaf(zr[k], zr[k], z2);

    float dmin = 3.4e38f, d2nd = 3.4e38f;
    int bidx = 0;
    const int n0 = wv << 7;
    #pragma unroll 1
    for (int nn = 0; nn < 128; ++nn) {
        const int n = n0 + nn;
        const float* ep = emb + (n << 6);                // uniform -> s_load
        float d0 = 0.f, d1 = 0.f, d2 = 0.f, d3 = 0.f;
        #pragma unroll
        for (int k = 0; k < 64; k += 4) {
            d0 = fmaf(zr[k + 0], ep[k + 0], d0);
            d1 = fmaf(zr[k + 1], ep[k + 1], d1);
            d2 = fmaf(zr[k + 2], ep[k + 2], d2);
            d3 = fmaf(zr[k + 3], ep[k + 3], d3);
        }
        float dot = (d0 + d1) + (d2 + d3);
        float d = z2 + e2[n] - 2.f * dot;
        if (d < dmin)      { d2nd = dmin; dmin = d; bidx = n; }
        else if (d < d2nd) { d2nd = d; }
    }
    dA[wv][lane] = dmin; d2A[wv][lane] = d2nd; iA[wv][lane] = bidx;
    __syncthreads();

    if (wv == 0) {
        float m1 = dA[0][lane], m2 = d2A[0][lane];
        int bi = iA[0][lane];
        #pragma unroll
        for (int p = 1; p < 4; ++p) {
            float a1 = dA[p][lane], a2 = d2A[p][lane]; int ai = iA[p][lane];
            if (a1 < m1) { m2 = fminf(m1, a2); m1 = a1; bi = ai; }
            else         { m2 = fminf(m2, a1); }       // a2 >= a1, so a1 suffices
        }
        iA[0][lane] = bi;                               // publish merged idx
        if (m2 - m1 < MARGIN) {                         // near-tie -> fp64 refine
            int pos = atomicAdd(cnt, 1);
            if (pos < CAP) wl[pos] = ((b << 6) + lane) * 64 + h;
        }
        float ms = m1;
        #pragma unroll
        for (int off = 32; off; off >>= 1) ms += __shfl_xor(ms, off, 64);
        if (lane == 0) atomicAdd(accs + 0, ms);
    }
    __syncthreads();

    // z_q write: wave wv writes channels [wv*16,(wv+1)*16), coalesced over lanes
    float* zrow = zq + ((size_t)(b * 64) << 12) + (h << 6) + lane;
    #pragma unroll 1
    for (int cc = 0; cc < 16; ++cc) {
        int c = wv * 16 + cc;
        int id = iA[0][c];                              // LDS broadcast
        zrow[(size_t)c << 12] = emb[(id << 6) + lane];
    }
}

// ============================================================
// K3b: fp64 refinement of flagged tokens (persistent grid-stride)
// ============================================================
__global__ __launch_bounds__(256) void refine(
    const float* __restrict__ x,
    const double* __restrict__ Wd,     // [o][f] double
    const double* __restrict__ bpd,    // [64] double
    const float* __restrict__ emb,     // [512][64]
    const float* __restrict__ eft,     // [64][512]
    const int* __restrict__ cnt, const int* __restrict__ wl,
    float* __restrict__ zq)
{
    int count = cnt[0]; if (count > CAP) count = CAP;
    const int tid = threadIdx.x, lane = tid & 63, wv = tid >> 6;

    __shared__ double zp[4][64];
    __shared__ double zs[64];
    __shared__ double dsh[256];
    __shared__ int    ish[256];

    for (int it = blockIdx.x; it < count; it += gridDim.x) {
        const int r = wl[it];
        const int b = r >> 12, c = (r >> 6) & 63, h = r & 63;

        const float* xp = x + (((size_t)(b * 256 + wv * 64)) << 12) + (h << 6) + lane;
        const double* wrow = Wd + c * 256 + wv * 64;
        double zd = 0.0;
        #pragma unroll 8
        for (int f = 0; f < 64; ++f)
            zd = fma(wrow[f], (double)xp[((size_t)f) << 12], zd);
        zp[wv][lane] = zd;
        __syncthreads();
        if (tid < 64) zs[tid] = (zp[0][tid] + zp[1][tid]) + (zp[2][tid] + zp[3][tid]) + bpd[c];
        __syncthreads();

        double dm = 1e300; int im = 0;
        #pragma unroll
        for (int jj = 0; jj < 2; ++jj) {
            int n = (jj << 8) + tid;
            double d = 0.0;
            #pragma unroll 8
            for (int k = 0; k < 64; ++k) {
                double t = zs[k] - (double)eft[(k << 9) + n];
                d = fma(t, t, d);
            }
            if (d < dm) { dm = d; im = n; }
        }
        dsh[tid] = dm; ish[tid] = im;
        __syncthreads();
        for (int st = 128; st; st >>= 1) {
            if (tid < st) {
                double od = dsh[tid + st]; int oi = ish[tid + st];
                if (od < dsh[tid] || (od == dsh[tid] && oi < ish[tid])) { dsh[tid] = od; ish[tid] = oi; }
            }
            __syncthreads();
        }
        if (tid < 64) {
            int idx = ish[0];
            zq[((size_t)r << 6) + tid] = emb[(idx << 6) + tid];
        }
        __syncthreads();
    }
}

// ============================================================
// K4: codebook angular stats (symmetric: col 2nd-min == row 2nd-min)
// ============================================================
__global__ __launch_bounds__(64) void cb_stats(
    const float* __restrict__ emb, const float* __restrict__ eft,
    const float* __restrict__ en, float* __restrict__ accs)
{
    __shared__ float ang[512];
    const int lane = threadIdx.x;
    const int i = blockIdx.x;
    const float eni = en[i];
    const float* ei = emb + (i << 6);    // uniform
    float m1 = 3.4e38f, m2 = 3.4e38f, ssum = 0.f;
    #pragma unroll 1
    for (int jj = 0; jj < 8; ++jj) {
        int j = (jj << 6) + lane;
        float d0 = 0.f, d1 = 0.f, d2 = 0.f, d3 = 0.f;
        #pragma unroll
        for (int k = 0; k < 64; k += 4) {
            d0 = fmaf(ei[k + 0], eft[(k + 0) * 512 + j], d0);
            d1 = fmaf(ei[k + 1], eft[(k + 1) * 512 + j], d1);
            d2 = fmaf(ei[k + 2], eft[(k + 2) * 512 + j], d2);
            d3 = fmaf(ei[k + 3], eft[(k + 3) * 512 + j], d3);
        }
        float dot = (d0 + d1) + (d2 + d3);
        float xv = dot / (eni * en[j]);
        xv = fminf(fmaxf(xv, -0.99999f), 0.99999f);
        float a = acosf(xv);
        ang[j] = a;
        ssum += a;
        if (a < m1) { m2 = m1; m1 = a; }
        else if (a < m2) m2 = a;
    }
    __syncthreads();
    #pragma unroll
    for (int off = 32; off; off >>= 1) ssum += __shfl_xor(ssum, off, 64);
    #pragma unroll
    for (int off = 32; off; off >>= 1) {
        float o1 = __shfl_xor(m1, off, 64);
        float o2 = __shfl_xor(m2, off, 64);
        if (o1 < m1) { m2 = fminf(m1, o2); m1 = o1; }
        else          m2 = fminf(m2, o1);
    }
    float mean = ssum * (1.f / 512.f);
    float vs = 0.f;
    #pragma unroll
    for (int jj = 0; jj < 8; ++jj) {
        float t = ang[(jj << 6) + lane] - mean;
        vs = fmaf(t, t, vs);
    }
    #pragma unroll
    for (int off = 32; off; off >>= 1) vs += __shfl_xor(vs, off, 64);
    if (lane == 0) {
        atomicAdd(accs + 1, vs * (1.f / 511.f));  // row variance (ddof=1)
        atomicAdd(accs + 2, m2);                  // row second-smallest
    }
}

// ============================================================
// K5: finalize scalars (fp32 out)
// ============================================================
__global__ __launch_bounds__(64) void finalize(
    const float* __restrict__ accs, const float* __restrict__ en,
    const float* __restrict__ r, float* __restrict__ out)
{
    const int lane = threadIdx.x;
    float hs = 0.f, rs = 0.f;
    #pragma unroll
    for (int jj = 0; jj < 8; ++jj) {
        int n = (jj << 6) + lane;
        float rv = r[n];
        float d = rv - en[n];
        hs = fmaf(d, d, hs);
        rs += fminf(fmaxf(rv, 0.9f), 1.1f);
    }
    #pragma unroll
    for (int off = 32; off; off >>= 1) { hs += __shfl_xor(hs, off, 64); rs += __shfl_xor(rs, off, 64); }
    if (lane == 0) {
        float hsw    = hs * (1.f / 512.f);
        float mean_r = rs * (1.f / 512.f);
        float mse    = accs[0] * (1.f / 4194304.f);
        float cbv    = accs[1] * (1.f / 512.f);
        float tmd    = accs[2] * (1.f / 512.f);
        float loss   = 2.f * mse + hsw + (cbv - tmd);   // beta=1 -> both commit terms equal
        out[0]       = loss;
        out[4194305] = cbv;
        out[4194306] = tmd;
        out[4194307] = hsw;
        out[4194308] = 0.f;                             // cb_loss = 0
        out[4194309] = mean_r;
    }
}

// ============================================================
extern "C" void kernel_launch(void* const* d_in, const int* in_sizes, int n_in,
                              void* d_out, int out_size, void* d_ws, size_t ws_size,
                              hipStream_t stream) {
    const float* x   = (const float*)d_in[0];
    const float* g1  = (const float*)d_in[1];
    const float* be1 = (const float*)d_in[2];
    const float* w1  = (const float*)d_in[3];
    const float* b1  = (const float*)d_in[4];
    const float* w2  = (const float*)d_in[5];
    const float* b2  = (const float*)d_in[6];
    const float* emb = (const float*)d_in[7];
    const float* r   = (const float*)d_in[8];
    float* ws = (float*)d_ws;
    float* out = (float*)d_out;

    double* AD   = (double*)(ws + WS_AD);
    double* CD   = (double*)(ws + WS_CD);
    double* WD   = (double*)(ws + WS_WD);
    double* PART = (double*)(ws + WS_WD);   // aliased: consumed before WD written
    double* BPD  = (double*)(ws + WS_BPD);
    int*    CNT  = (int*)(ws + WS_CNT);
    int*    WL   = (int*)(ws + WS_WL);

    bn_partial<<<1024, 256, 0, stream>>>(x, PART);
    bn_final<<<1, 256, 0, stream>>>(PART, g1, be1, AD, CD);
    prep_w<<<64, 256, 0, stream>>>(w1, w2, AD, emb, ws + WS_WT, WD,
                                   ws + WS_EFT, ws + WS_EN, ws + WS_E2);
    prep_bias<<<1, 256, 0, stream>>>(w1, w2, b1, b2, CD,
                                     ws + WS_BP, BPD, ws + WS_ACC, CNT);
    fused_gemm_vq<<<1024, 256, 0, stream>>>(x, ws + WS_WT, ws + WS_BP,
                                            emb, ws + WS_E2, ws + WS_ACC,
                                            CNT, WL, out + 1);
    refine<<<256, 256, 0, stream>>>(x, WD, BPD, emb, ws + WS_EFT, CNT, WL, out + 1);
    cb_stats<<<512, 64, 0, stream>>>(emb, ws + WS_EFT, ws + WS_EN, ws + WS_ACC);
    finalize<<<1, 64, 0, stream>>>(ws + WS_ACC, ws + WS_EN, r, out);
}

// Round 7
// 299.298 us; speedup vs baseline: 2.3337x; 1.8107x over previous
//
#include <hip/hip_runtime.h>
#include <math.h>

// ---------- problem constants ----------
// B=16, F=256, C=64, H=64, W=64, N_E=512. Inputs fp32, outputs fp32.
// tokens: rows r=(b*64+c)*64+h of 64 w-values; 65536 tokens total.
// fp32 main pass; tokens with top-2 gap < MARGIN re-resolved in fp64.

#define CAP    2048
#define MARGIN 4e-3f

// ---------- workspace layout (float offsets; doubles at even offsets) ----------
#define WS_WT   0        // [16384]   W' float [f][o]
#define WS_BP   16384    // [64]      fused bias float
#define WS_EN   16448    // [512]     code norms
#define WS_E2   16960    // [512]     code sq-norms
#define WS_ACC  17472    // [8]       accumulators: 0=mse 1=var 2=tmd
#define WS_CNT  17480    // [8]       int counter region
#define WS_WL   17488    // [2048]    int worklist
#define WS_EFT  19536    // [64*512]  embedding fp32 transposed [k][n]
#define WS_AD   52304    // [256 dbl] bn scale a_f
#define WS_CD   52816    // [256 dbl] bn shift c_f
#define WS_WD   53328    // [16384 dbl] W' double [o][f]  (aliased: bn partials before prep_w)
#define WS_BPD  86096    // [64 dbl]  fused bias double

// async global->LDS, 16B per lane. LDS dest = uniform base + lane*16.
__device__ __forceinline__ void load_lds16(const float* g, float* l) {
    __builtin_amdgcn_global_load_lds((const __attribute__((address_space(1))) void*)g,
                                     (__attribute__((address_space(3))) void*)l, 16, 0, 0);
}

// ============================================================
// K1a: BN partial sums (fp64). grid 1024 = f*4 + chunk; chunk = 4 batches.
// ============================================================
__global__ __launch_bounds__(256) void bn_partial(
    const float* __restrict__ x, double* __restrict__ part)
{
    const int f = blockIdx.x >> 2, ch = blockIdx.x & 3, t = threadIdx.x;
    double s = 0.0, q = 0.0;
    #pragma unroll
    for (int bb = 0; bb < 4; ++bb) {
        const int b = ch * 4 + bb;
        const float4* p = (const float4*)(x + ((size_t)(b * 256 + f) << 12));
        #pragma unroll
        for (int ii = 0; ii < 4; ++ii) {
            float4 u = p[t + ii * 256];
            double dx = u.x, dy = u.y, dz = u.z, dw = u.w;
            s += (dx + dy) + (dz + dw);
            q = fma(dx, dx, q); q = fma(dy, dy, q);
            q = fma(dz, dz, q); q = fma(dw, dw, q);
        }
    }
    #pragma unroll
    for (int off = 32; off; off >>= 1) { s += __shfl_xor(s, off, 64); q += __shfl_xor(q, off, 64); }
    __shared__ double sh[8];
    const int wv = t >> 6;
    if ((t & 63) == 0) { sh[wv * 2] = s; sh[wv * 2 + 1] = q; }
    __syncthreads();
    if (t == 0) {
        part[blockIdx.x * 2]     = (sh[0] + sh[2]) + (sh[4] + sh[6]);
        part[blockIdx.x * 2 + 1] = (sh[1] + sh[3]) + (sh[5] + sh[7]);
    }
}

// ============================================================
// K1b: finalize BN -> a_f, c_f (fp64)
// ============================================================
__global__ __launch_bounds__(256) void bn_final(
    const double* __restrict__ part,
    const float* __restrict__ gamma, const float* __restrict__ beta,
    double* __restrict__ ad, double* __restrict__ cd)
{
    const int f = threadIdx.x;
    double s = 0.0, q = 0.0;
    #pragma unroll
    for (int c = 0; c < 4; ++c) { s += part[(f * 4 + c) * 2]; q += part[(f * 4 + c) * 2 + 1]; }
    double mean = s * (1.0 / 65536.0);
    double var  = q * (1.0 / 65536.0) - mean * mean;
    double a = (double)gamma[f] / sqrt(var + 1e-5);
    ad[f] = a;
    cd[f] = (double)beta[f] - mean * a;
}

// ============================================================
// K2a: W' fold (fp64) + embedding transpose/norms. 64 blocks x 256.
// ============================================================
__global__ __launch_bounds__(256) void prep_w(
    const float* __restrict__ w1,   // [64][256]
    const float* __restrict__ w2,   // [64][64]
    const double* __restrict__ ad,
    const float* __restrict__ emb,  // [512][64]
    float* __restrict__ Wt,         // float [f][o]
    double* __restrict__ Wd,        // double [o][f]
    float* __restrict__ eft, float* __restrict__ en, float* __restrict__ e2)
{
    const int t = threadIdx.x;
    const int o = t & 63, fi = t >> 6;
    const int f = blockIdx.x * 4 + fi;
    double s = 0.0;
    for (int c = 0; c < 64; ++c)
        s = fma((double)w2[o * 64 + c], (double)w1[c * 256 + f], s);
    double wp = s * ad[f];
    Wd[o * 256 + f] = wp;
    Wt[f * 64 + o]  = (float)wp;

    // embedding rows for this block: n in [blk*8, blk*8+8); wave wv covers 2 rows
    const int lane = t & 63, wv = t >> 6;
    #pragma unroll
    for (int rr = 0; rr < 2; ++rr) {
        int n = blockIdx.x * 8 + rr * 4 + wv;
        float v = emb[n * 64 + lane];
        eft[lane * 512 + n] = v;
        float qq = v * v;
        #pragma unroll
        for (int off = 32; off; off >>= 1) qq += __shfl_xor(qq, off, 64);
        if (lane == 0) { e2[n] = qq; en[n] = sqrtf(qq); }
    }
}

// ============================================================
// K2b: fp64 fused bias b'; zero accs/counter. 1 block x 256.
// ============================================================
__global__ __launch_bounds__(256) void prep_bias(
    const float* __restrict__ w1,
    const float* __restrict__ w2,
    const float* __restrict__ b1,
    const float* __restrict__ b2,
    const double* __restrict__ cd,
    float* __restrict__ bp, double* __restrict__ bpd,
    float* __restrict__ accs, int* __restrict__ cnt)
{
    __shared__ double red[4][64];
    __shared__ double tsh[64];
    const int t = threadIdx.x;
    const int o = t & 63, p = t >> 6;
    double s = 0.0;
    for (int j = 0; j < 64; ++j) {
        int fidx = p * 64 + j;
        s = fma((double)w1[o * 256 + fidx], cd[fidx], s);
    }
    red[p][o] = s; __syncthreads();
    if (t < 64) tsh[t] = (double)b1[t] + (red[0][t] + red[1][t]) + (red[2][t] + red[3][t]);
    __syncthreads();
    if (t < 64) {
        double bb = (double)b2[t];
        for (int c = 0; c < 64; ++c)
            bb = fma((double)w2[t * 64 + c], tsh[c], bb);
        bpd[t] = bb;
        bp[t]  = (float)bb;
    }
    if (t < 8) accs[t] = 0.f;
    if (t == 0) cnt[0] = 0;
}

// ============================================================
// K3: fused GEMM + VQ. Block = 4 waves per (b,h).
// Round-6 lesson: wv=tid>>6-derived pointers are DIVERGENT to the compiler ->
// per-lane broadcast VMEM loads, trickling 2-4 at a time under reg pressure ->
// ~500K stall cycles/wave. Fixes: (a) readfirstlane(wv) => W' loads become
// s_load; (b) VQ codes staged wave-locally into the dead zsB region via async
// global_load_lds, read back as LDS broadcasts (identical values/order).
// ============================================================
__global__ __launch_bounds__(256, 2) void fused_gemm_vq(
    const float* __restrict__ x,
    const float* __restrict__ Wt,      // [256 f][64 o]
    const float* __restrict__ bp,      // [64]
    const float* __restrict__ emb,     // [512][64] fp32
    const float* __restrict__ e2,      // [512]
    float* __restrict__ accs,
    int* __restrict__ cnt, int* __restrict__ wl,
    float* __restrict__ zq)            // = out+1, fp32
{
    __shared__ __align__(16) float zsA[64 * 65];
    __shared__ __align__(16) float zsB[64 * 65];   // reused as VQ code staging after merge
    __shared__ float dA[4][64];
    __shared__ float d2A[4][64];
    __shared__ int   iA[4][64];
    __shared__ float e2s[512];

    const int tid = threadIdx.x, lane = tid & 63, wv = tid >> 6;
    const int wvu = __builtin_amdgcn_readfirstlane(wv);   // SGPR wave id
    const int b = blockIdx.x >> 6;
    const int h = blockIdx.x & 63;

    float acc[64];
    #pragma unroll
    for (int c = 0; c < 64; ++c) acc[c] = 0.f;

    const float* xb = x + ((size_t)(b * 256 + wvu * 64) << 12) + (h << 6) + lane;
    const float* wp = Wt + wvu * 64 * 64;              // uniform -> s_load
    #pragma unroll 4
    for (int i = 0; i < 64; ++i) {
        float xv = xb[(size_t)i << 12];
        #pragma unroll
        for (int c = 0; c < 64; ++c)
            acc[c] = fmaf(wp[i * 64 + c], xv, acc[c]);
    }

    // e2 -> LDS (once per block)
    e2s[tid]       = e2[tid];
    e2s[tid + 256] = e2[tid + 256];

    // tree-reduce partials: (0,+2) -> zsA, (1,+3) -> zsB, then zsA += zsB
    if (wv == 0) {
        #pragma unroll
        for (int c = 0; c < 64; ++c) zsA[c * 65 + lane] = acc[c] + bp[c];
    } else if (wv == 1) {
        #pragma unroll
        for (int c = 0; c < 64; ++c) zsB[c * 65 + lane] = acc[c];
    }
    __syncthreads();
    if (wv == 2) {
        #pragma unroll
        for (int c = 0; c < 64; ++c) zsA[c * 65 + lane] += acc[c];
    } else if (wv == 3) {
        #pragma unroll
        for (int c = 0; c < 64; ++c) zsB[c * 65 + lane] += acc[c];
    }
    __syncthreads();
    #pragma unroll
    for (int cc = 0; cc < 16; ++cc) {
        int c = wv * 16 + cc;
        zsA[c * 65 + lane] += zsB[c * 65 + lane];
    }
    __syncthreads();
    // ---- zsB is now dead; becomes per-wave VQ code staging (4KB each) ----
    float* stage = zsB + wvu * 1024;                   // 16 codes x 64 floats
    const int n0 = wvu << 7;                           // this wave's code base

    // stage tile 0 (codes n0..n0+15): 4 async issues of 1KB
    {
        const float* gp = emb + (size_t)n0 * 64;
        #pragma unroll
        for (int j = 0; j < 4; ++j)
            load_lds16(gp + j * 256 + lane * 4, stage + j * 256);
    }

    // VQ: lane = token (channel c=lane); this wave scans codes [n0, n0+128)
    float zr[64];
    #pragma unroll
    for (int k = 0; k < 64; ++k) zr[k] = zsA[lane * 65 + k];
    float z2 = 0.f;
    #pragma unroll
    for (int k = 0; k < 64; ++k) z2 = fmaf(zr[k], zr[k], z2);

    float dmin = 3.4e38f, d2nd = 3.4e38f;
    int bidx = 0;
    #pragma unroll 1
    for (int t8 = 0; t8 < 8; ++t8) {
        __builtin_amdgcn_s_waitcnt(0x0F70);            // vmcnt(0): tile staged
        #pragma unroll 1
        for (int cc = 0; cc < 16; ++cc) {
            const float* ep = stage + cc * 64;         // LDS broadcast reads
            const int n = n0 + t8 * 16 + cc;
            float d0 = 0.f, d1 = 0.f, d2 = 0.f, d3 = 0.f;
            #pragma unroll
            for (int k = 0; k < 64; k += 4) {
                d0 = fmaf(zr[k + 0], ep[k + 0], d0);
                d1 = fmaf(zr[k + 1], ep[k + 1], d1);
                d2 = fmaf(zr[k + 2], ep[k + 2], d2);
                d3 = fmaf(zr[k + 3], ep[k + 3], d3);
            }
            float dot = (d0 + d1) + (d2 + d3);
            float d = z2 + e2s[n] - 2.f * dot;
            if (d < dmin)      { d2nd = dmin; dmin = d; bidx = n; }
            else if (d < d2nd) { d2nd = d; }
        }
        if (t8 < 7) {                                  // stage next tile
            const float* gp = emb + (size_t)(n0 + (t8 + 1) * 16) * 64;
            #pragma unroll
            for (int j = 0; j < 4; ++j)
                load_lds16(gp + j * 256 + lane * 4, stage + j * 256);
        }
    }
    dA[wv][lane] = dmin; d2A[wv][lane] = d2nd; iA[wv][lane] = bidx;
    __syncthreads();

    if (wv == 0) {
        float m1 = dA[0][lane], m2 = d2A[0][lane];
        int bi = iA[0][lane];
        #pragma unroll
        for (int p = 1; p < 4; ++p) {
            float a1 = dA[p][lane], a2 = d2A[p][lane]; int ai = iA[p][lane];
            if (a1 < m1) { m2 = fminf(m1, a2); m1 = a1; bi = ai; }
            else         { m2 = fminf(m2, a1); }       // a2 >= a1, so a1 suffices
        }
        iA[0][lane] = bi;                               // publish merged idx
        if (m2 - m1 < MARGIN) {                         // near-tie -> fp64 refine
            int pos = atomicAdd(cnt, 1);
            if (pos < CAP) wl[pos] = ((b << 6) + lane) * 64 + h;
        }
        float ms = m1;
        #pragma unroll
        for (int off = 32; off; off >>= 1) ms += __shfl_xor(ms, off, 64);
        if (lane == 0) atomicAdd(accs + 0, ms);
    }
    __syncthreads();

    // z_q write: wave wv writes channels [wv*16,(wv+1)*16), coalesced over lanes
    float* zrow = zq + ((size_t)(b * 64) << 12) + (h << 6) + lane;
    #pragma unroll 1
    for (int cc = 0; cc < 16; ++cc) {
        int c = wvu * 16 + cc;
        int id = iA[0][c];                              // LDS broadcast
        zrow[(size_t)c << 12] = emb[(id << 6) + lane];
    }
}

// ============================================================
// K3b: fp64 refinement of flagged tokens (persistent grid-stride)
// ============================================================
__global__ __launch_bounds__(256) void refine(
    const float* __restrict__ x,
    const double* __restrict__ Wd,     // [o][f] double
    const double* __restrict__ bpd,    // [64] double
    const float* __restrict__ emb,     // [512][64]
    const float* __restrict__ eft,     // [64][512]
    const int* __restrict__ cnt, const int* __restrict__ wl,
    float* __restrict__ zq)
{
    int count = cnt[0]; if (count > CAP) count = CAP;
    const int tid = threadIdx.x, lane = tid & 63, wv = tid >> 6;

    __shared__ double zp[4][64];
    __shared__ double zs[64];
    __shared__ double dsh[256];
    __shared__ int    ish[256];

    for (int it = blockIdx.x; it < count; it += gridDim.x) {
        const int r = wl[it];
        const int b = r >> 12, c = (r >> 6) & 63, h = r & 63;

        const float* xp = x + (((size_t)(b * 256 + wv * 64)) << 12) + (h << 6) + lane;
        const double* wrow = Wd + c * 256 + wv * 64;
        double zd = 0.0;
        #pragma unroll 8
        for (int f = 0; f < 64; ++f)
            zd = fma(wrow[f], (double)xp[((size_t)f) << 12], zd);
        zp[wv][lane] = zd;
        __syncthreads();
        if (tid < 64) zs[tid] = (zp[0][tid] + zp[1][tid]) + (zp[2][tid] + zp[3][tid]) + bpd[c];
        __syncthreads();

        double dm = 1e300; int im = 0;
        #pragma unroll
        for (int jj = 0; jj < 2; ++jj) {
            int n = (jj << 8) + tid;
            double d = 0.0;
            #pragma unroll 8
            for (int k = 0; k < 64; ++k) {
                double t = zs[k] - (double)eft[(k << 9) + n];
                d = fma(t, t, d);
            }
            if (d < dm) { dm = d; im = n; }
        }
        dsh[tid] = dm; ish[tid] = im;
        __syncthreads();
        for (int st = 128; st; st >>= 1) {
            if (tid < st) {
                double od = dsh[tid + st]; int oi = ish[tid + st];
                if (od < dsh[tid] || (od == dsh[tid] && oi < ish[tid])) { dsh[tid] = od; ish[tid] = oi; }
            }
            __syncthreads();
        }
        if (tid < 64) {
            int idx = ish[0];
            zq[((size_t)r << 6) + tid] = emb[(idx << 6) + tid];
        }
        __syncthreads();
    }
}

// ============================================================
// K4: codebook angular stats (symmetric: col 2nd-min == row 2nd-min)
// ============================================================
__global__ __launch_bounds__(64) void cb_stats(
    const float* __restrict__ emb, const float* __restrict__ eft,
    const float* __restrict__ en, float* __restrict__ accs)
{
    __shared__ float ang[512];
    const int lane = threadIdx.x;
    const int i = blockIdx.x;
    const float eni = en[i];
    const float* ei = emb + (i << 6);    // uniform
    float m1 = 3.4e38f, m2 = 3.4e38f, ssum = 0.f;
    #pragma unroll 1
    for (int jj = 0; jj < 8; ++jj) {
        int j = (jj << 6) + lane;
        float d0 = 0.f, d1 = 0.f, d2 = 0.f, d3 = 0.f;
        #pragma unroll
        for (int k = 0; k < 64; k += 4) {
            d0 = fmaf(ei[k + 0], eft[(k + 0) * 512 + j], d0);
            d1 = fmaf(ei[k + 1], eft[(k + 1) * 512 + j], d1);
            d2 = fmaf(ei[k + 2], eft[(k + 2) * 512 + j], d2);
            d3 = fmaf(ei[k + 3], eft[(k + 3) * 512 + j], d3);
        }
        float dot = (d0 + d1) + (d2 + d3);
        float xv = dot / (eni * en[j]);
        xv = fminf(fmaxf(xv, -0.99999f), 0.99999f);
        float a = acosf(xv);
        ang[j] = a;
        ssum += a;
        if (a < m1) { m2 = m1; m1 = a; }
        else if (a < m2) m2 = a;
    }
    __syncthreads();
    #pragma unroll
    for (int off = 32; off; off >>= 1) ssum += __shfl_xor(ssum, off, 64);
    #pragma unroll
    for (int off = 32; off; off >>= 1) {
        float o1 = __shfl_xor(m1, off, 64);
        float o2 = __shfl_xor(m2, off, 64);
        if (o1 < m1) { m2 = fminf(m1, o2); m1 = o1; }
        else          m2 = fminf(m2, o1);
    }
    float mean = ssum * (1.f / 512.f);
    float vs = 0.f;
    #pragma unroll
    for (int jj = 0; jj < 8; ++jj) {
        float t = ang[(jj << 6) + lane] - mean;
        vs = fmaf(t, t, vs);
    }
    #pragma unroll
    for (int off = 32; off; off >>= 1) vs += __shfl_xor(vs, off, 64);
    if (lane == 0) {
        atomicAdd(accs + 1, vs * (1.f / 511.f));  // row variance (ddof=1)
        atomicAdd(accs + 2, m2);                  // row second-smallest
    }
}

// ============================================================
// K5: finalize scalars (fp32 out)
// ============================================================
__global__ __launch_bounds__(64) void finalize(
    const float* __restrict__ accs, const float* __restrict__ en,
    const float* __restrict__ r, float* __restrict__ out)
{
    const int lane = threadIdx.x;
    float hs = 0.f, rs = 0.f;
    #pragma unroll
    for (int jj = 0; jj < 8; ++jj) {
        int n = (jj << 6) + lane;
        float rv = r[n];
        float d = rv - en[n];
        hs = fmaf(d, d, hs);
        rs += fminf(fmaxf(rv, 0.9f), 1.1f);
    }
    #pragma unroll
    for (int off = 32; off; off >>= 1) { hs += __shfl_xor(hs, off, 64); rs += __shfl_xor(rs, off, 64); }
    if (lane == 0) {
        float hsw    = hs * (1.f / 512.f);
        float mean_r = rs * (1.f / 512.f);
        float mse    = accs[0] * (1.f / 4194304.f);
        float cbv    = accs[1] * (1.f / 512.f);
        float tmd    = accs[2] * (1.f / 512.f);
        float loss   = 2.f * mse + hsw + (cbv - tmd);   // beta=1 -> both commit terms equal
        out[0]       = loss;
        out[4194305] = cbv;
        out[4194306] = tmd;
        out[4194307] = hsw;
        out[4194308] = 0.f;                             // cb_loss = 0
        out[4194309] = mean_r;
    }
}

// ============================================================
extern "C" void kernel_launch(void* const* d_in, const int* in_sizes, int n_in,
                              void* d_out, int out_size, void* d_ws, size_t ws_size,
                              hipStream_t stream) {
    const float* x   = (const float*)d_in[0];
    const float* g1  = (const float*)d_in[1];
    const float* be1 = (const float*)d_in[2];
    const float* w1  = (const float*)d_in[3];
    const float* b1  = (const float*)d_in[4];
    const float* w2  = (const float*)d_in[5];
    const float* b2  = (const float*)d_in[6];
    const float* emb = (const float*)d_in[7];
    const float* r   = (const float*)d_in[8];
    float* ws = (float*)d_ws;
    float* out = (float*)d_out;

    double* AD   = (double*)(ws + WS_AD);
    double* CD   = (double*)(ws + WS_CD);
    double* WD   = (double*)(ws + WS_WD);
    double* PART = (double*)(ws + WS_WD);   // aliased: consumed before WD written
    double* BPD  = (double*)(ws + WS_BPD);
    int*    CNT  = (int*)(ws + WS_CNT);
    int*    WL   = (int*)(ws + WS_WL);

    bn_partial<<<1024, 256, 0, stream>>>(x, PART);
    bn_final<<<1, 256, 0, stream>>>(PART, g1, be1, AD, CD);
    prep_w<<<64, 256, 0, stream>>>(w1, w2, AD, emb, ws + WS_WT, WD,
                                   ws + WS_EFT, ws + WS_EN, ws + WS_E2);
    prep_bias<<<1, 256, 0, stream>>>(w1, w2, b1, b2, CD,
                                     ws + WS_BP, BPD, ws + WS_ACC, CNT);
    fused_gemm_vq<<<1024, 256, 0, stream>>>(x, ws + WS_WT, ws + WS_BP,
                                            emb, ws + WS_E2, ws + WS_ACC,
                                            CNT, WL, out + 1);
    refine<<<256, 256, 0, stream>>>(x, WD, BPD, emb, ws + WS_EFT, CNT, WL, out + 1);
    cb_stats<<<512, 64, 0, stream>>>(emb, ws + WS_EFT, ws + WS_EN, ws + WS_ACC);
    finalize<<<1, 64, 0, stream>>>(ws + WS_ACC, ws + WS_EN, r, out);
}

// Round 8
// 280.186 us; speedup vs baseline: 2.4929x; 1.0682x over previous
//
#include <hip/hip_runtime.h>
#include <math.h>

// ---------- problem constants ----------
// B=16, F=256, C=64, H=64, W=64, N_E=512. Inputs fp32, outputs fp32.
// tokens: rows r=(b*64+c)*64+h of 64 w-values; 65536 tokens total.
// fp32 main pass; tokens with top-2 gap < MARGIN re-resolved in fp64.

#define CAP    2048
#define MARGIN 4e-3f

// ---------- workspace layout (float offsets; doubles at even offsets) ----------
#define WS_WT   0        // [16384]   W' float [f][o]
#define WS_BP   16384    // [64]      fused bias float
#define WS_EN   16448    // [512]     code norms
#define WS_E2   16960    // [512]     code sq-norms
#define WS_ACC  17472    // [8]       accumulators: 0=mse 1=var 2=tmd
#define WS_CNT  17480    // [8]       int counter region
#define WS_WL   17488    // [2048]    int worklist
#define WS_EFT  19536    // [64*512]  embedding fp32 transposed [k][n]
#define WS_WD   52304    // [16384 dbl] W' double [o][f]
#define WS_BPD  85072    // [64 dbl]  fused bias double
#define WS_PART 85200    // [512*2 dbl] bn partials  (ends 87248 floats < proven 88784)

// async global->LDS, 16B per lane. LDS dest = uniform base + lane*16.
__device__ __forceinline__ void load_lds16(const float* g, float* l) {
    __builtin_amdgcn_global_load_lds((const __attribute__((address_space(1))) void*)g,
                                     (__attribute__((address_space(3))) void*)l, 16, 0, 0);
}

// ============================================================
// K1: BN partial sums (fp64). grid 512 = f*2 + chunk; chunk = 8 batches.
// ============================================================
__global__ __launch_bounds__(256) void bn_partial(
    const float* __restrict__ x, double* __restrict__ part)
{
    const int f = blockIdx.x >> 1, ch = blockIdx.x & 1, t = threadIdx.x;
    double s = 0.0, q = 0.0;
    #pragma unroll 1
    for (int bb = 0; bb < 8; ++bb) {
        const int b = ch * 8 + bb;
        const float4* p = (const float4*)(x + ((size_t)(b * 256 + f) << 12));
        #pragma unroll
        for (int ii = 0; ii < 4; ++ii) {
            float4 u = p[t + ii * 256];
            double dx = u.x, dy = u.y, dz = u.z, dw = u.w;
            s += (dx + dy) + (dz + dw);
            q = fma(dx, dx, q); q = fma(dy, dy, q);
            q = fma(dz, dz, q); q = fma(dw, dw, q);
        }
    }
    #pragma unroll
    for (int off = 32; off; off >>= 1) { s += __shfl_xor(s, off, 64); q += __shfl_xor(q, off, 64); }
    __shared__ double sh[8];
    const int wv = t >> 6;
    if ((t & 63) == 0) { sh[wv * 2] = s; sh[wv * 2 + 1] = q; }
    __syncthreads();
    if (t == 0) {
        part[blockIdx.x * 2]     = (sh[0] + sh[2]) + (sh[4] + sh[6]);
        part[blockIdx.x * 2 + 1] = (sh[1] + sh[3]) + (sh[5] + sh[7]);
    }
}

// ============================================================
// K2: prep. Blocks 0..63: a_f from partials + W' fold (fp64) + emb transpose.
//          Block 64: c_f from partials + fused bias b' + zero accs/cnt.
// ============================================================
__global__ __launch_bounds__(256) void prep(
    const float* __restrict__ w1,   // [64][256]
    const float* __restrict__ w2,   // [64][64]
    const float* __restrict__ b1,
    const float* __restrict__ b2,
    const float* __restrict__ gamma,
    const float* __restrict__ beta,
    const float* __restrict__ emb,  // [512][64]
    const double* __restrict__ part,
    float* __restrict__ Wt, double* __restrict__ Wd,
    double* __restrict__ bpd, float* __restrict__ bp,
    float* __restrict__ eft, float* __restrict__ en, float* __restrict__ e2,
    float* __restrict__ accs, int* __restrict__ cnt)
{
    __shared__ double sh_ad[4];
    __shared__ double cdl[256];
    __shared__ double red[4][64];
    __shared__ double tsh[64];
    const int t = threadIdx.x;

    if (blockIdx.x < 64) {
        const int o = t & 63, fi = t >> 6;
        const int f = blockIdx.x * 4 + fi;
        if (o == 0) {
            double s = part[(2 * f) * 2]     + part[(2 * f + 1) * 2];
            double q = part[(2 * f) * 2 + 1] + part[(2 * f + 1) * 2 + 1];
            double mean = s * (1.0 / 65536.0);
            double var  = q * (1.0 / 65536.0) - mean * mean;
            sh_ad[fi] = (double)gamma[f] / sqrt(var + 1e-5);
        }
        __syncthreads();
        double s = 0.0;
        for (int c = 0; c < 64; ++c)
            s = fma((double)w2[o * 64 + c], (double)w1[c * 256 + f], s);
        double wp = s * sh_ad[fi];
        Wd[o * 256 + f] = wp;
        Wt[f * 64 + o]  = (float)wp;

        // embedding rows: n in [blk*8, blk*8+8); wave wv covers 2 rows
        const int lane = t & 63, wv = t >> 6;
        #pragma unroll
        for (int rr = 0; rr < 2; ++rr) {
            int n = blockIdx.x * 8 + rr * 4 + wv;
            float v = emb[n * 64 + lane];
            eft[lane * 512 + n] = v;
            float qq = v * v;
            #pragma unroll
            for (int off = 32; off; off >>= 1) qq += __shfl_xor(qq, off, 64);
            if (lane == 0) { e2[n] = qq; en[n] = sqrtf(qq); }
        }
    } else {
        // block 64: bias path
        {
            const int f = t;
            double s = part[(2 * f) * 2]     + part[(2 * f + 1) * 2];
            double q = part[(2 * f) * 2 + 1] + part[(2 * f + 1) * 2 + 1];
            double mean = s * (1.0 / 65536.0);
            double var  = q * (1.0 / 65536.0) - mean * mean;
            double a = (double)gamma[f] / sqrt(var + 1e-5);
            cdl[f] = (double)beta[f] - mean * a;
        }
        __syncthreads();
        const int o = t & 63, p = t >> 6;
        double ss = 0.0;
        for (int j = 0; j < 64; ++j) {
            int fidx = p * 64 + j;
            ss = fma((double)w1[o * 256 + fidx], cdl[fidx], ss);
        }
        red[p][o] = ss; __syncthreads();
        if (t < 64) tsh[t] = (double)b1[t] + (red[0][t] + red[1][t]) + (red[2][t] + red[3][t]);
        __syncthreads();
        if (t < 64) {
            double bb = (double)b2[t];
            for (int c = 0; c < 64; ++c)
                bb = fma((double)w2[t * 64 + c], tsh[c], bb);
            bpd[t] = bb;
            bp[t]  = (float)bb;
        }
        if (t < 8) accs[t] = 0.f;
        if (t == 0) cnt[0] = 0;
    }
}

// ============================================================
// K3: blocks 0..1023: fused GEMM + VQ per (b,h), 4 waves.
//     blocks 1024..1535: codebook angular stats (row i = blockIdx-1024).
// GEMM: 8-deep register prefetch of x. VQ: double-buffered LDS staging
// (zsA dead after zr extraction -> second buffer), prefetch 2 tiles ahead,
// wait vmcnt(4) so a full tile-compute hides each tile's load latency.
// ============================================================
__global__ __launch_bounds__(256, 2) void fused_gemm_vq(
    const float* __restrict__ x,
    const float* __restrict__ Wt,      // [256 f][64 o]
    const float* __restrict__ bp,      // [64]
    const float* __restrict__ emb,     // [512][64] fp32
    const float* __restrict__ e2,      // [512]
    const float* __restrict__ en,      // [512]
    const float* __restrict__ eft,     // [64][512]
    float* __restrict__ accs,
    int* __restrict__ cnt, int* __restrict__ wl,
    float* __restrict__ zq)            // = out+1, fp32
{
    __shared__ __align__(16) float zsA[64 * 65];
    __shared__ __align__(16) float zsB[64 * 65];
    __shared__ float dA[4][64];
    __shared__ float d2A[4][64];
    __shared__ int   iA[4][64];
    __shared__ float e2s[512];          // cb path reuses as ang[512]

    const int tid = threadIdx.x, lane = tid & 63, wv = tid >> 6;

    // ---------------- codebook-stats blocks ----------------
    if (blockIdx.x >= 1024) {
        const int i = blockIdx.x - 1024;
        float* ang = e2s;
        const float eni = en[i];
        const float* ei = emb + (i << 6);       // uniform -> s_load
        #pragma unroll
        for (int jj = 0; jj < 2; ++jj) {
            const int j = tid + jj * 256;
            float d0 = 0.f, d1 = 0.f, d2 = 0.f, d3 = 0.f;
            #pragma unroll
            for (int k = 0; k < 64; k += 4) {
                d0 = fmaf(ei[k + 0], eft[(k + 0) * 512 + j], d0);
                d1 = fmaf(ei[k + 1], eft[(k + 1) * 512 + j], d1);
                d2 = fmaf(ei[k + 2], eft[(k + 2) * 512 + j], d2);
                d3 = fmaf(ei[k + 3], eft[(k + 3) * 512 + j], d3);
            }
            float dot = (d0 + d1) + (d2 + d3);
            float xv = dot / (eni * en[j]);
            xv = fminf(fmaxf(xv, -0.99999f), 0.99999f);
            ang[j] = acosf(xv);
        }
        __syncthreads();
        if (wv == 0) {
            float m1 = 3.4e38f, m2 = 3.4e38f, ssum = 0.f;
            #pragma unroll
            for (int t8 = 0; t8 < 8; ++t8) {
                float a = ang[t8 * 64 + lane];
                ssum += a;
                if (a < m1) { m2 = m1; m1 = a; }
                else if (a < m2) m2 = a;
            }
            #pragma unroll
            for (int off = 32; off; off >>= 1) ssum += __shfl_xor(ssum, off, 64);
            #pragma unroll
            for (int off = 32; off; off >>= 1) {
                float o1 = __shfl_xor(m1, off, 64);
                float o2 = __shfl_xor(m2, off, 64);
                if (o1 < m1) { m2 = fminf(m1, o2); m1 = o1; }
                else          m2 = fminf(m2, o1);
            }
            float mean = ssum * (1.f / 512.f);
            float vs = 0.f;
            #pragma unroll
            for (int t8 = 0; t8 < 8; ++t8) {
                float tt = ang[t8 * 64 + lane] - mean;
                vs = fmaf(tt, tt, vs);
            }
            #pragma unroll
            for (int off = 32; off; off >>= 1) vs += __shfl_xor(vs, off, 64);
            if (lane == 0) {
                atomicAdd(accs + 1, vs * (1.f / 511.f));
                atomicAdd(accs + 2, m2);
            }
        }
        return;
    }

    // ---------------- main GEMM+VQ blocks ----------------
    const int wvu = __builtin_amdgcn_readfirstlane(wv);   // SGPR wave id
    const int b = blockIdx.x >> 6;
    const int h = blockIdx.x & 63;

    float acc[64];
    #pragma unroll
    for (int c = 0; c < 64; ++c) acc[c] = 0.f;

    const float* xb = x + ((size_t)(b * 256 + wvu * 64) << 12) + (h << 6) + lane;
    const float* wp = Wt + wvu * 64 * 64;              // uniform -> s_load

    float xcur[8], xnxt[8];
    #pragma unroll
    for (int j = 0; j < 8; ++j) xcur[j] = xb[(size_t)j << 12];
    #pragma unroll 1
    for (int i8 = 0; i8 < 8; ++i8) {
        if (i8 < 7) {
            #pragma unroll
            for (int j = 0; j < 8; ++j) xnxt[j] = xb[(size_t)((i8 + 1) * 8 + j) << 12];
        }
        #pragma unroll
        for (int j = 0; j < 8; ++j) {
            const float* wrow = wp + (i8 * 8 + j) * 64;
            #pragma unroll
            for (int c = 0; c < 64; ++c)
                acc[c] = fmaf(wrow[c], xcur[j], acc[c]);
        }
        if (i8 < 7) {
            #pragma unroll
            for (int j = 0; j < 8; ++j) xcur[j] = xnxt[j];
        }
    }

    // e2 -> LDS (once per block)
    e2s[tid]       = e2[tid];
    e2s[tid + 256] = e2[tid + 256];

    // tree-reduce partials: (0,+2) -> zsA, (1,+3) -> zsB, then zsA += zsB
    if (wv == 0) {
        #pragma unroll
        for (int c = 0; c < 64; ++c) zsA[c * 65 + lane] = acc[c] + bp[c];
    } else if (wv == 1) {
        #pragma unroll
        for (int c = 0; c < 64; ++c) zsB[c * 65 + lane] = acc[c];
    }
    __syncthreads();
    if (wv == 2) {
        #pragma unroll
        for (int c = 0; c < 64; ++c) zsA[c * 65 + lane] += acc[c];
    } else if (wv == 3) {
        #pragma unroll
        for (int c = 0; c < 64; ++c) zsB[c * 65 + lane] += acc[c];
    }
    __syncthreads();
    #pragma unroll
    for (int cc = 0; cc < 16; ++cc) {
        int c = wv * 16 + cc;
        zsA[c * 65 + lane] += zsB[c * 65 + lane];
    }
    __syncthreads();

    // VQ: lane = token (channel c=lane); this wave scans codes [n0, n0+128)
    float zr[64];
    #pragma unroll
    for (int k = 0; k < 64; ++k) zr[k] = zsA[lane * 65 + k];
    float z2 = 0.f;
    #pragma unroll
    for (int k = 0; k < 64; ++k) z2 = fmaf(zr[k], zr[k], z2);
    __syncthreads();   // all waves done reading zsA -> zsA/zsB become staging

    float* stA = zsA + wvu * 1024;                     // 16 codes x 64 floats
    float* stB = zsB + wvu * 1024;
    const int n0 = wvu << 7;

    {   // prologue: stage tiles 0 and 1
        const float* gp = emb + (size_t)n0 * 64;
        #pragma unroll
        for (int j = 0; j < 4; ++j) load_lds16(gp + j * 256 + lane * 4, stA + j * 256);
        gp += 1024;
        #pragma unroll
        for (int j = 0; j < 4; ++j) load_lds16(gp + j * 256 + lane * 4, stB + j * 256);
    }

    float dmin = 3.4e38f, d2nd = 3.4e38f;
    int bidx = 0;
    #pragma unroll 1
    for (int t8 = 0; t8 < 8; ++t8) {
        if (t8 < 7) __builtin_amdgcn_s_waitcnt(0x0F74);   // vmcnt(4): this tile done
        else        __builtin_amdgcn_s_waitcnt(0x0F70);   // vmcnt(0): last tile
        const float* cur = (t8 & 1) ? stB : stA;
        #pragma unroll 1
        for (int cc = 0; cc < 16; ++cc) {
            const float* ep = cur + cc * 64;           // LDS broadcast reads
            const int n = n0 + t8 * 16 + cc;
            float d0 = 0.f, d1 = 0.f, d2 = 0.f, d3 = 0.f;
            #pragma unroll
            for (int k = 0; k < 64; k += 4) {
                d0 = fmaf(zr[k + 0], ep[k + 0], d0);
                d1 = fmaf(zr[k + 1], ep[k + 1], d1);
                d2 = fmaf(zr[k + 2], ep[k + 2], d2);
                d3 = fmaf(zr[k + 3], ep[k + 3], d3);
            }
            float dot = (d0 + d1) + (d2 + d3);
            float d = z2 + e2s[n] - 2.f * dot;
            if (d < dmin)      { d2nd = dmin; dmin = d; bidx = n; }
            else if (d < d2nd) { d2nd = d; }
        }
        if (t8 + 2 < 8) {                              // stage tile t8+2 into just-freed buffer
            const float* gp = emb + (size_t)(n0 + (t8 + 2) * 16) * 64;
            float* dst = (t8 & 1) ? stB : stA;
            #pragma unroll
            for (int j = 0; j < 4; ++j) load_lds16(gp + j * 256 + lane * 4, dst + j * 256);
        }
    }
    dA[wv][lane] = dmin; d2A[wv][lane] = d2nd; iA[wv][lane] = bidx;
    __syncthreads();

    if (wv == 0) {
        float m1 = dA[0][lane], m2 = d2A[0][lane];
        int bi = iA[0][lane];
        #pragma unroll
        for (int p = 1; p < 4; ++p) {
            float a1 = dA[p][lane], a2 = d2A[p][lane]; int ai = iA[p][lane];
            if (a1 < m1) { m2 = fminf(m1, a2); m1 = a1; bi = ai; }
            else         { m2 = fminf(m2, a1); }
        }
        iA[0][lane] = bi;                               // publish merged idx
        if (m2 - m1 < MARGIN) {                         // near-tie -> fp64 refine
            int pos = atomicAdd(cnt, 1);
            if (pos < CAP) wl[pos] = ((b << 6) + lane) * 64 + h;
        }
        float ms = m1;
        #pragma unroll
        for (int off = 32; off; off >>= 1) ms += __shfl_xor(ms, off, 64);
        if (lane == 0) atomicAdd(accs + 0, ms);
    }
    __syncthreads();

    // z_q write: wave wv writes channels [wv*16,(wv+1)*16), coalesced over lanes
    float* zrow = zq + ((size_t)(b * 64) << 12) + (h << 6) + lane;
    #pragma unroll 1
    for (int cc = 0; cc < 16; ++cc) {
        int c = wvu * 16 + cc;
        int id = iA[0][c];                              // LDS broadcast
        zrow[(size_t)c << 12] = emb[(id << 6) + lane];
    }
}

// ============================================================
// K4: fp64 refinement (blocks 0..255, persistent) + finalize (block 256)
// ============================================================
__global__ __launch_bounds__(256) void refine_fin(
    const float* __restrict__ x,
    const double* __restrict__ Wd,     // [o][f] double
    const double* __restrict__ bpd,    // [64] double
    const float* __restrict__ emb,     // [512][64]
    const float* __restrict__ eft,     // [64][512]
    const int* __restrict__ cnt, const int* __restrict__ wl,
    float* __restrict__ zq,
    const float* __restrict__ accs, const float* __restrict__ en,
    const float* __restrict__ r, float* __restrict__ out)
{
    const int tid = threadIdx.x, lane = tid & 63, wv = tid >> 6;

    if (blockIdx.x == 256) {           // ---- finalize scalars ----
        if (wv == 0) {
            float hs = 0.f, rs = 0.f;
            #pragma unroll
            for (int jj = 0; jj < 8; ++jj) {
                int n = (jj << 6) + lane;
                float rv = r[n];
                float d = rv - en[n];
                hs = fmaf(d, d, hs);
                rs += fminf(fmaxf(rv, 0.9f), 1.1f);
            }
            #pragma unroll
            for (int off = 32; off; off >>= 1) { hs += __shfl_xor(hs, off, 64); rs += __shfl_xor(rs, off, 64); }
            if (lane == 0) {
                float hsw    = hs * (1.f / 512.f);
                float mean_r = rs * (1.f / 512.f);
                float mse    = accs[0] * (1.f / 4194304.f);
                float cbv    = accs[1] * (1.f / 512.f);
                float tmd    = accs[2] * (1.f / 512.f);
                float loss   = 2.f * mse + hsw + (cbv - tmd);
                out[0]       = loss;
                out[4194305] = cbv;
                out[4194306] = tmd;
                out[4194307] = hsw;
                out[4194308] = 0.f;
                out[4194309] = mean_r;
            }
        }
        return;
    }

    int count = cnt[0]; if (count > CAP) count = CAP;

    __shared__ double zp[4][64];
    __shared__ double zs[64];
    __shared__ double dsh[256];
    __shared__ int    ish[256];

    for (int it = blockIdx.x; it < count; it += 256) {
        const int r2 = wl[it];
        const int b = r2 >> 12, c = (r2 >> 6) & 63, h = r2 & 63;

        const float* xp = x + (((size_t)(b * 256 + wv * 64)) << 12) + (h << 6) + lane;
        const double* wrow = Wd + c * 256 + wv * 64;
        double zd = 0.0;
        #pragma unroll 8
        for (int f = 0; f < 64; ++f)
            zd = fma(wrow[f], (double)xp[((size_t)f) << 12], zd);
        zp[wv][lane] = zd;
        __syncthreads();
        if (tid < 64) zs[tid] = (zp[0][tid] + zp[1][tid]) + (zp[2][tid] + zp[3][tid]) + bpd[c];
        __syncthreads();

        double dm = 1e300; int im = 0;
        #pragma unroll
        for (int jj = 0; jj < 2; ++jj) {
            int n = (jj << 8) + tid;
            double d = 0.0;
            #pragma unroll 8
            for (int k = 0; k < 64; ++k) {
                double t = zs[k] - (double)eft[(k << 9) + n];
                d = fma(t, t, d);
            }
            if (d < dm) { dm = d; im = n; }
        }
        dsh[tid] = dm; ish[tid] = im;
        __syncthreads();
        for (int st = 128; st; st >>= 1) {
            if (tid < st) {
                double od = dsh[tid + st]; int oi = ish[tid + st];
                if (od < dsh[tid] || (od == dsh[tid] && oi < ish[tid])) { dsh[tid] = od; ish[tid] = oi; }
            }
            __syncthreads();
        }
        if (tid < 64) {
            int idx = ish[0];
            zq[((size_t)r2 << 6) + tid] = emb[(idx << 6) + tid];
        }
        __syncthreads();
    }
}

// ============================================================
extern "C" void kernel_launch(void* const* d_in, const int* in_sizes, int n_in,
                              void* d_out, int out_size, void* d_ws, size_t ws_size,
                              hipStream_t stream) {
    const float* x   = (const float*)d_in[0];
    const float* g1  = (const float*)d_in[1];
    const float* be1 = (const float*)d_in[2];
    const float* w1  = (const float*)d_in[3];
    const float* b1  = (const float*)d_in[4];
    const float* w2  = (const float*)d_in[5];
    const float* b2  = (const float*)d_in[6];
    const float* emb = (const float*)d_in[7];
    const float* r   = (const float*)d_in[8];
    float* ws = (float*)d_ws;
    float* out = (float*)d_out;

    double* WD   = (double*)(ws + WS_WD);
    double* BPD  = (double*)(ws + WS_BPD);
    double* PART = (double*)(ws + WS_PART);
    int*    CNT  = (int*)(ws + WS_CNT);
    int*    WL   = (int*)(ws + WS_WL);

    bn_partial<<<512, 256, 0, stream>>>(x, PART);
    prep<<<65, 256, 0, stream>>>(w1, w2, b1, b2, g1, be1, emb, PART,
                                 ws + WS_WT, WD, BPD, ws + WS_BP,
                                 ws + WS_EFT, ws + WS_EN, ws + WS_E2,
                                 ws + WS_ACC, CNT);
    fused_gemm_vq<<<1536, 256, 0, stream>>>(x, ws + WS_WT, ws + WS_BP,
                                            emb, ws + WS_E2, ws + WS_EN, ws + WS_EFT,
                                            ws + WS_ACC, CNT, WL, out + 1);
    refine_fin<<<257, 256, 0, stream>>>(x, WD, BPD, emb, ws + WS_EFT, CNT, WL,
                                        out + 1, ws + WS_ACC, ws + WS_EN, r, out);
}

// Round 9
// 255.542 us; speedup vs baseline: 2.7333x; 1.0964x over previous
//
#include <hip/hip_runtime.h>
#include <math.h>

// ---------- problem constants ----------
// B=16, F=256, C=64, H=64, W=64, N_E=512. Inputs fp32, outputs fp32.
// tokens: rows r=(b*64+c)*64+h of 64 w-values; 65536 tokens total.
// fp32 GEMM -> bf16-split MFMA VQ; tokens with top-2 gap < MARGIN re-resolved in fp64.

#define CAP    2048
#define MARGIN 4e-3f

// ---------- workspace layout (float offsets) ----------
#define WS_WT   0        // [16384]   W' float [f][o]
#define WS_BP   16384    // [64]
#define WS_EN   16448    // [512]
#define WS_E2   16960    // [512]
#define WS_ACC  17472    // [8]
#define WS_CNT  17480    // [8]
#define WS_WL   17488    // [2048]
#define WS_EFT  19536    // [64*512] fp32 emb^T
#define WS_WD   52304    // [16384 dbl]
#define WS_BPD  85072    // [64 dbl]
#define WS_PART 85200    // [1024 dbl] bn partials
#define WS_EHI  87248    // [32768 ushort] emb hi bf16, XOR-swizzled granules
#define WS_ELO  103632   // [32768 ushort] emb lo bf16, swizzled  (ends 120016 floats)

typedef __attribute__((ext_vector_type(8))) __bf16 bf16v8;
typedef __attribute__((ext_vector_type(4))) float  f32v4;

__device__ __forceinline__ unsigned short f2bf(float f) {
    union { float f; unsigned u; } v; v.f = f;
    unsigned r = v.u + 0x7FFFu + ((v.u >> 16) & 1u);
    return (unsigned short)(r >> 16);
}
__device__ __forceinline__ float bf2f(unsigned short h) {
    union { unsigned u; float f; } v; v.u = ((unsigned)h) << 16; return v.f;
}
__device__ __forceinline__ void load_lds16(const float* g, unsigned* l) {
    __builtin_amdgcn_global_load_lds((const __attribute__((address_space(1))) void*)g,
                                     (__attribute__((address_space(3))) void*)l, 16, 0, 0);
}

// ============================================================
// K1: BN partial sums (fp64). grid 512 = f*2 + chunk; chunk = 8 batches.
// ============================================================
__global__ __launch_bounds__(256) void bn_partial(
    const float* __restrict__ x, double* __restrict__ part)
{
    const int f = blockIdx.x >> 1, ch = blockIdx.x & 1, t = threadIdx.x;
    double s = 0.0, q = 0.0;
    #pragma unroll 1
    for (int bb = 0; bb < 8; ++bb) {
        const int b = ch * 8 + bb;
        const float4* p = (const float4*)(x + ((size_t)(b * 256 + f) << 12));
        #pragma unroll
        for (int ii = 0; ii < 4; ++ii) {
            float4 u = p[t + ii * 256];
            double dx = u.x, dy = u.y, dz = u.z, dw = u.w;
            s += (dx + dy) + (dz + dw);
            q = fma(dx, dx, q); q = fma(dy, dy, q);
            q = fma(dz, dz, q); q = fma(dw, dw, q);
        }
    }
    #pragma unroll
    for (int off = 32; off; off >>= 1) { s += __shfl_xor(s, off, 64); q += __shfl_xor(q, off, 64); }
    __shared__ double sh[8];
    const int wv = t >> 6;
    if ((t & 63) == 0) { sh[wv * 2] = s; sh[wv * 2 + 1] = q; }
    __syncthreads();
    if (t == 0) {
        part[blockIdx.x * 2]     = (sh[0] + sh[2]) + (sh[4] + sh[6]);
        part[blockIdx.x * 2 + 1] = (sh[1] + sh[3]) + (sh[5] + sh[7]);
    }
}

// ============================================================
// K2: prep. Blocks 0..63: a_f + W' fold (fp64) + emb transpose + bf16 hi/lo split.
//          Block 64: c_f + fused bias b' + zero accs/cnt.
// ============================================================
__global__ __launch_bounds__(256) void prep(
    const float* __restrict__ w1, const float* __restrict__ w2,
    const float* __restrict__ b1, const float* __restrict__ b2,
    const float* __restrict__ gamma, const float* __restrict__ beta,
    const float* __restrict__ emb, const double* __restrict__ part,
    float* __restrict__ Wt, double* __restrict__ Wd,
    double* __restrict__ bpd, float* __restrict__ bp,
    float* __restrict__ eft, float* __restrict__ en, float* __restrict__ e2,
    unsigned short* __restrict__ ehi, unsigned short* __restrict__ elo,
    float* __restrict__ accs, int* __restrict__ cnt)
{
    __shared__ double sh_ad[4];
    __shared__ double cdl[256];
    __shared__ double red[4][64];
    __shared__ double tsh[64];
    const int t = threadIdx.x;

    if (blockIdx.x < 64) {
        const int o = t & 63, fi = t >> 6;
        const int f = blockIdx.x * 4 + fi;
        if (o == 0) {
            double s = part[(2 * f) * 2]     + part[(2 * f + 1) * 2];
            double q = part[(2 * f) * 2 + 1] + part[(2 * f + 1) * 2 + 1];
            double mean = s * (1.0 / 65536.0);
            double var  = q * (1.0 / 65536.0) - mean * mean;
            sh_ad[fi] = (double)gamma[f] / sqrt(var + 1e-5);
        }
        __syncthreads();
        double s = 0.0;
        for (int c = 0; c < 64; ++c)
            s = fma((double)w2[o * 64 + c], (double)w1[c * 256 + f], s);
        double wp = s * sh_ad[fi];
        Wd[o * 256 + f] = wp;
        Wt[f * 64 + o]  = (float)wp;

        // embedding rows: n in [blk*8, blk*8+8); wave wv covers 2 rows; lane = k
        const int lane = t & 63, wv = t >> 6;
        #pragma unroll
        for (int rr = 0; rr < 2; ++rr) {
            int n = blockIdx.x * 8 + rr * 4 + wv;
            float v = emb[n * 64 + lane];
            eft[lane * 512 + n] = v;
            unsigned short hb = f2bf(v);
            unsigned short lb = f2bf(v - bf2f(hb));
            int pos = (lane >> 3) ^ (n & 7);          // XOR-swizzled granule
            ehi[n * 64 + pos * 8 + (lane & 7)] = hb;
            elo[n * 64 + pos * 8 + (lane & 7)] = lb;
            float qq = v * v;
            #pragma unroll
            for (int off = 32; off; off >>= 1) qq += __shfl_xor(qq, off, 64);
            if (lane == 0) { e2[n] = qq; en[n] = sqrtf(qq); }
        }
    } else {
        {
            const int f = t;
            double s = part[(2 * f) * 2]     + part[(2 * f + 1) * 2];
            double q = part[(2 * f) * 2 + 1] + part[(2 * f + 1) * 2 + 1];
            double mean = s * (1.0 / 65536.0);
            double var  = q * (1.0 / 65536.0) - mean * mean;
            double a = (double)gamma[f] / sqrt(var + 1e-5);
            cdl[f] = (double)beta[f] - mean * a;
        }
        __syncthreads();
        const int o = t & 63, p = t >> 6;
        double ss = 0.0;
        for (int j = 0; j < 64; ++j) {
            int fidx = p * 64 + j;
            ss = fma((double)w1[o * 256 + fidx], cdl[fidx], ss);
        }
        red[p][o] = ss; __syncthreads();
        if (t < 64) tsh[t] = (double)b1[t] + (red[0][t] + red[1][t]) + (red[2][t] + red[3][t]);
        __syncthreads();
        if (t < 64) {
            double bb = (double)b2[t];
            for (int c = 0; c < 64; ++c)
                bb = fma((double)w2[t * 64 + c], tsh[c], bb);
            bpd[t] = bb;
            bp[t]  = (float)bb;
        }
        if (t < 8) accs[t] = 0.f;
        if (t == 0) cnt[0] = 0;
    }
}

// ============================================================
// K3: blocks 0..1023: fused GEMM (fp32 VALU) + VQ (bf16-split MFMA) per (b,h).
//     blocks 1024..1535: codebook angular stats.
// VQ: Dot[64 tok x 512 codes] via mfma_f32_16x16x32_bf16, 4 split terms
// (hi*hi + hi*lo + lo*hi + lo*lo), fp32 accumulate. Wave w owns M-tile w.
// Codes staged 32/tile via global_load_lds double buffer (1 barrier/tile);
// XOR-swizzled granules make fragment ds_read_b128 2-way-only (free).
// ============================================================
__global__ __launch_bounds__(256, 2) void fused_gemm_vq(
    const float* __restrict__ x,
    const float* __restrict__ Wt,
    const float* __restrict__ bp,
    const float* __restrict__ emb,
    const float* __restrict__ e2,
    const float* __restrict__ en,
    const float* __restrict__ eft,
    const unsigned short* __restrict__ ehi,
    const unsigned short* __restrict__ elo,
    float* __restrict__ accs,
    int* __restrict__ cnt, int* __restrict__ wl,
    float* __restrict__ zq)
{
    __shared__ __align__(16) unsigned smem[9280];
    enum { OZS = 0, OZHI = 4160, OZLO = 6208, OE2 = 8256, OZ2 = 8768,
           OPART = 8832, ODT = 9088, OD2T = 9152, OIT = 9216 };
    float* zsA = (float*)(smem + OZS);     // fp32 z, stride 65; later: staging overlay
    float* zsT = (float*)(smem + OZHI);    // fp32 temp during reduction (then bf16 z_hi)
    float* e2s = (float*)(smem + OE2);
    float* z2s = (float*)(smem + OZ2);
    float* prt = (float*)(smem + OPART);
    float* dT  = (float*)(smem + ODT);
    float* d2T = (float*)(smem + OD2T);
    int*   iT  = (int*)(smem + OIT);

    const int tid = threadIdx.x, lane = tid & 63, wv = tid >> 6;

    // ---------------- codebook-stats blocks ----------------
    if (blockIdx.x >= 1024) {
        const int i = blockIdx.x - 1024;
        float* ang = e2s;                   // 512 floats
        const float eni = en[i];
        const float* ei = emb + (i << 6);
        #pragma unroll
        for (int jj = 0; jj < 2; ++jj) {
            const int j = tid + jj * 256;
            float d0 = 0.f, d1 = 0.f, d2 = 0.f, d3 = 0.f;
            #pragma unroll
            for (int k = 0; k < 64; k += 4) {
                d0 = fmaf(ei[k + 0], eft[(k + 0) * 512 + j], d0);
                d1 = fmaf(ei[k + 1], eft[(k + 1) * 512 + j], d1);
                d2 = fmaf(ei[k + 2], eft[(k + 2) * 512 + j], d2);
                d3 = fmaf(ei[k + 3], eft[(k + 3) * 512 + j], d3);
            }
            float dot = (d0 + d1) + (d2 + d3);
            float xv = dot / (eni * en[j]);
            xv = fminf(fmaxf(xv, -0.99999f), 0.99999f);
            ang[j] = acosf(xv);
        }
        __syncthreads();
        if (wv == 0) {
            float m1 = 3.4e38f, m2 = 3.4e38f, ssum = 0.f;
            #pragma unroll
            for (int t8 = 0; t8 < 8; ++t8) {
                float a = ang[t8 * 64 + lane];
                ssum += a;
                if (a < m1) { m2 = m1; m1 = a; }
                else if (a < m2) m2 = a;
            }
            #pragma unroll
            for (int off = 32; off; off >>= 1) ssum += __shfl_xor(ssum, off, 64);
            #pragma unroll
            for (int off = 32; off; off >>= 1) {
                float o1 = __shfl_xor(m1, off, 64);
                float o2 = __shfl_xor(m2, off, 64);
                if (o1 < m1) { m2 = fminf(m1, o2); m1 = o1; }
                else          m2 = fminf(m2, o1);
            }
            float mean = ssum * (1.f / 512.f);
            float vs = 0.f;
            #pragma unroll
            for (int t8 = 0; t8 < 8; ++t8) {
                float tt = ang[t8 * 64 + lane] - mean;
                vs = fmaf(tt, tt, vs);
            }
            #pragma unroll
            for (int off = 32; off; off >>= 1) vs += __shfl_xor(vs, off, 64);
            if (lane == 0) {
                atomicAdd(accs + 1, vs * (1.f / 511.f));
                atomicAdd(accs + 2, m2);
            }
        }
        return;
    }

    // ---------------- main GEMM+VQ blocks ----------------
    const int wvu = __builtin_amdgcn_readfirstlane(wv);
    const int b = blockIdx.x >> 6, h = blockIdx.x & 63;

    // e2 -> LDS
    e2s[tid]       = e2[tid];
    e2s[tid + 256] = e2[tid + 256];

    // ---- fp32 GEMM: wave wv accumulates features [wv*64,(wv+1)*64) ----
    float acc[64];
    #pragma unroll
    for (int c = 0; c < 64; ++c) acc[c] = 0.f;
    const float* xb = x + ((size_t)(b * 256 + wvu * 64) << 12) + (h << 6) + lane;
    const float* wp = Wt + wvu * 64 * 64;
    float xcur[8], xnxt[8];
    #pragma unroll
    for (int j = 0; j < 8; ++j) xcur[j] = xb[(size_t)j << 12];
    #pragma unroll 1
    for (int i8 = 0; i8 < 8; ++i8) {
        if (i8 < 7) {
            #pragma unroll
            for (int j = 0; j < 8; ++j) xnxt[j] = xb[(size_t)((i8 + 1) * 8 + j) << 12];
        }
        #pragma unroll
        for (int j = 0; j < 8; ++j) {
            const float* wrow = wp + (i8 * 8 + j) * 64;
            #pragma unroll
            for (int c = 0; c < 64; ++c)
                acc[c] = fmaf(wrow[c], xcur[j], acc[c]);
        }
        if (i8 < 7) {
            #pragma unroll
            for (int j = 0; j < 8; ++j) xcur[j] = xnxt[j];
        }
    }

    // ---- reduction (same summation order as r8: ((a0+bp)+a2)+(a1+a3)) ----
    if (wv == 0) {
        #pragma unroll
        for (int c = 0; c < 64; ++c) zsA[c * 65 + lane] = acc[c] + bp[c];
    } else if (wv == 1) {
        #pragma unroll
        for (int c = 0; c < 64; ++c) zsT[c * 64 + lane] = acc[c];
    }
    __syncthreads();
    if (wv == 2) {
        #pragma unroll
        for (int c = 0; c < 64; ++c) zsA[c * 65 + lane] += acc[c];
    } else if (wv == 3) {
        #pragma unroll
        for (int c = 0; c < 64; ++c) zsT[c * 64 + lane] += acc[c];
    }
    __syncthreads();
    #pragma unroll
    for (int cc = 0; cc < 16; ++cc) {
        int c = wv * 16 + cc;
        zsA[c * 65 + lane] += zsT[c * 64 + lane];
    }
    __syncthreads();

    // ---- convert z -> bf16 hi/lo (swizzled granules) + z2 partials ----
    {
        const int k0 = wvu * 16;     // this wave's k-range; token = lane
        float zv[16];
        #pragma unroll
        for (int j = 0; j < 16; ++j) zv[j] = zsA[lane * 65 + k0 + j];
        float p2 = 0.f;
        #pragma unroll
        for (int j = 0; j < 16; ++j) p2 = fmaf(zv[j], zv[j], p2);
        prt[wvu * 64 + lane] = p2;
        #pragma unroll
        for (int w2 = 0; w2 < 8; ++w2) {
            int k = k0 + 2 * w2;
            unsigned short h0 = f2bf(zv[2 * w2]), h1 = f2bf(zv[2 * w2 + 1]);
            unsigned short l0 = f2bf(zv[2 * w2] - bf2f(h0));
            unsigned short l1 = f2bf(zv[2 * w2 + 1] - bf2f(h1));
            int g = k >> 3;
            int pos = g ^ (lane & 7);
            int widx = lane * 32 + pos * 4 + ((k & 7) >> 1);
            smem[OZHI + widx] = (unsigned)h0 | ((unsigned)h1 << 16);
            smem[OZLO + widx] = (unsigned)l0 | ((unsigned)l1 << 16);
        }
    }
    __syncthreads();   // zhi/zlo ready; zsA region dead -> staging buffers

    if (wvu == 0) {
        z2s[lane] = (prt[lane] + prt[64 + lane]) + (prt[128 + lane] + prt[192 + lane]);
        const float* gh = (const float*)ehi;   // tile 0
        const float* gl = (const float*)elo;
        #pragma unroll
        for (int j = 0; j < 4; ++j) load_lds16(gh + j * 256 + lane * 4, smem + OZS + j * 256);
        #pragma unroll
        for (int j = 0; j < 4; ++j) load_lds16(gl + j * 256 + lane * 4, smem + OZS + 1024 + j * 256);
    }

    // A-fragments (fixed per lane): token m = wv*16 + (lane&15), granule s*4+quad
    const int cq = lane & 15, qd = lane >> 4;
    bf16v8 ahi[2], alo[2];
    {
        const int rbase = (wvu * 16 + cq) * 32;
        const int x7 = cq & 7;
        #pragma unroll
        for (int s = 0; s < 2; ++s) {
            int pos = ((s * 4 + qd) ^ x7) * 4;
            ahi[s] = *(const bf16v8*)(smem + OZHI + rbase + pos);
            alo[s] = *(const bf16v8*)(smem + OZLO + rbase + pos);
        }
    }

    float z2r[4];
    float m1[4] = {3.4e38f, 3.4e38f, 3.4e38f, 3.4e38f};
    float m2[4] = {3.4e38f, 3.4e38f, 3.4e38f, 3.4e38f};
    int   i1[4] = {0, 0, 0, 0};
    const int x7 = cq & 7;
    const int p0 = (qd ^ x7) * 4, p1 = ((4 + qd) ^ x7) * 4;

    #pragma unroll 1
    for (int t2 = 0; t2 < 32; ++t2) {
        if ((t2 & 1) == 0) {
            __syncthreads();                       // staged tile (t2>>1) ready
            int st = t2 >> 1;
            if (wvu == 0 && st < 15) {             // prefetch next tile
                const float* gh = (const float*)ehi + (size_t)(st + 1) * 1024;
                const float* gl = (const float*)elo + (size_t)(st + 1) * 1024;
                unsigned* dst = smem + OZS + ((st + 1) & 1) * 2048;
                #pragma unroll
                for (int j = 0; j < 4; ++j) load_lds16(gh + j * 256 + lane * 4, dst + j * 256);
                #pragma unroll
                for (int j = 0; j < 4; ++j) load_lds16(gl + j * 256 + lane * 4, dst + 1024 + j * 256);
            }
            if (t2 == 0) {
                #pragma unroll
                for (int r = 0; r < 4; ++r) z2r[r] = z2s[wvu * 16 + qd * 4 + r];
            }
        }
        const int rb = OZS + ((t2 >> 1) & 1) * 2048 + ((t2 & 1) * 16 + cq) * 32;
        bf16v8 bh0 = *(const bf16v8*)(smem + rb + p0);
        bf16v8 bh1 = *(const bf16v8*)(smem + rb + p1);
        bf16v8 bl0 = *(const bf16v8*)(smem + rb + 1024 + p0);
        bf16v8 bl1 = *(const bf16v8*)(smem + rb + 1024 + p1);
        f32v4 a0 = {0.f, 0.f, 0.f, 0.f}, a1 = {0.f, 0.f, 0.f, 0.f};
        a0 = __builtin_amdgcn_mfma_f32_16x16x32_bf16(ahi[0], bh0, a0, 0, 0, 0);
        a1 = __builtin_amdgcn_mfma_f32_16x16x32_bf16(ahi[1], bh1, a1, 0, 0, 0);
        a0 = __builtin_amdgcn_mfma_f32_16x16x32_bf16(ahi[0], bl0, a0, 0, 0, 0);
        a1 = __builtin_amdgcn_mfma_f32_16x16x32_bf16(ahi[1], bl1, a1, 0, 0, 0);
        a0 = __builtin_amdgcn_mfma_f32_16x16x32_bf16(alo[0], bh0, a0, 0, 0, 0);
        a1 = __builtin_amdgcn_mfma_f32_16x16x32_bf16(alo[1], bh1, a1, 0, 0, 0);
        a0 = __builtin_amdgcn_mfma_f32_16x16x32_bf16(alo[0], bl0, a0, 0, 0, 0);
        a1 = __builtin_amdgcn_mfma_f32_16x16x32_bf16(alo[1], bl1, a1, 0, 0, 0);
        const float eps = e2s[t2 * 16 + cq];
        const int n = t2 * 16 + cq;
        #pragma unroll
        for (int r = 0; r < 4; ++r) {
            float d = fmaf(-2.f, a0[r] + a1[r], z2r[r] + eps);
            if (d < m1[r])      { m2[r] = m1[r]; m1[r] = d; i1[r] = n; }
            else if (d < m2[r]) { m2[r] = d; }
        }
    }

    // merge top-2 across the 16 columns of each lane group (tokens identical)
    #pragma unroll
    for (int r = 0; r < 4; ++r) {
        #pragma unroll
        for (int off = 1; off <= 8; off <<= 1) {
            float o1 = __shfl_xor(m1[r], off, 64);
            float o2 = __shfl_xor(m2[r], off, 64);
            int   oi = __shfl_xor(i1[r], off, 64);
            if (o1 < m1[r] || (o1 == m1[r] && oi < i1[r])) {
                m2[r] = fminf(m1[r], o2); m1[r] = o1; i1[r] = oi;
            } else {
                m2[r] = fminf(m2[r], o1);
            }
        }
    }
    if (cq == 0) {
        #pragma unroll
        for (int r = 0; r < 4; ++r) {
            int tok = wvu * 16 + qd * 4 + r;
            dT[tok] = m1[r]; d2T[tok] = m2[r]; iT[tok] = i1[r];
        }
    }
    __syncthreads();

    if (wv == 0) {
        float mm1 = dT[lane], mm2 = d2T[lane];
        if (mm2 - mm1 < MARGIN) {               // near-tie -> fp64 refine
            int pos = atomicAdd(cnt, 1);
            if (pos < CAP) wl[pos] = ((b << 6) + lane) * 64 + h;
        }
        float ms = mm1;
        #pragma unroll
        for (int off = 32; off; off >>= 1) ms += __shfl_xor(ms, off, 64);
        if (lane == 0) atomicAdd(accs + 0, ms);
    }
    __syncthreads();

    // z_q write: wave wv writes channels [wv*16,(wv+1)*16)
    float* zrow = zq + ((size_t)(b * 64) << 12) + (h << 6) + lane;
    #pragma unroll 1
    for (int cc = 0; cc < 16; ++cc) {
        int c = wvu * 16 + cc;
        int id = iT[c];
        zrow[(size_t)c << 12] = emb[(id << 6) + lane];
    }
}

// ============================================================
// K4: fp64 refinement (blocks 0..255, persistent) + finalize (block 256)
// ============================================================
__global__ __launch_bounds__(256) void refine_fin(
    const float* __restrict__ x,
    const double* __restrict__ Wd,
    const double* __restrict__ bpd,
    const float* __restrict__ emb,
    const float* __restrict__ eft,
    const int* __restrict__ cnt, const int* __restrict__ wl,
    float* __restrict__ zq,
    const float* __restrict__ accs, const float* __restrict__ en,
    const float* __restrict__ r, float* __restrict__ out)
{
    const int tid = threadIdx.x, lane = tid & 63, wv = tid >> 6;

    if (blockIdx.x == 256) {
        if (wv == 0) {
            float hs = 0.f, rs = 0.f;
            #pragma unroll
            for (int jj = 0; jj < 8; ++jj) {
                int n = (jj << 6) + lane;
                float rv = r[n];
                float d = rv - en[n];
                hs = fmaf(d, d, hs);
                rs += fminf(fmaxf(rv, 0.9f), 1.1f);
            }
            #pragma unroll
            for (int off = 32; off; off >>= 1) { hs += __shfl_xor(hs, off, 64); rs += __shfl_xor(rs, off, 64); }
            if (lane == 0) {
                float hsw    = hs * (1.f / 512.f);
                float mean_r = rs * (1.f / 512.f);
                float mse    = accs[0] * (1.f / 4194304.f);
                float cbv    = accs[1] * (1.f / 512.f);
                float tmd    = accs[2] * (1.f / 512.f);
                float loss   = 2.f * mse + hsw + (cbv - tmd);
                out[0]       = loss;
                out[4194305] = cbv;
                out[4194306] = tmd;
                out[4194307] = hsw;
                out[4194308] = 0.f;
                out[4194309] = mean_r;
            }
        }
        return;
    }

    int count = cnt[0]; if (count > CAP) count = CAP;

    __shared__ double zp[4][64];
    __shared__ double zs[64];
    __shared__ double dsh[256];
    __shared__ int    ish[256];

    for (int it = blockIdx.x; it < count; it += 256) {
        const int r2 = wl[it];
        const int b = r2 >> 12, c = (r2 >> 6) & 63, h = r2 & 63;

        const float* xp = x + (((size_t)(b * 256 + wv * 64)) << 12) + (h << 6) + lane;
        const double* wrow = Wd + c * 256 + wv * 64;
        double zd = 0.0;
        #pragma unroll 8
        for (int f = 0; f < 64; ++f)
            zd = fma(wrow[f], (double)xp[((size_t)f) << 12], zd);
        zp[wv][lane] = zd;
        __syncthreads();
        if (tid < 64) zs[tid] = (zp[0][tid] + zp[1][tid]) + (zp[2][tid] + zp[3][tid]) + bpd[c];
        __syncthreads();

        double dm = 1e300; int im = 0;
        #pragma unroll
        for (int jj = 0; jj < 2; ++jj) {
            int n = (jj << 8) + tid;
            double d = 0.0;
            #pragma unroll 8
            for (int k = 0; k < 64; ++k) {
                double t = zs[k] - (double)eft[(k << 9) + n];
                d = fma(t, t, d);
            }
            if (d < dm) { dm = d; im = n; }
        }
        dsh[tid] = dm; ish[tid] = im;
        __syncthreads();
        for (int st = 128; st; st >>= 1) {
            if (tid < st) {
                double od = dsh[tid + st]; int oi = ish[tid + st];
                if (od < dsh[tid] || (od == dsh[tid] && oi < ish[tid])) { dsh[tid] = od; ish[tid] = oi; }
            }
            __syncthreads();
        }
        if (tid < 64) {
            int idx = ish[0];
            zq[((size_t)r2 << 6) + tid] = emb[(idx << 6) + tid];
        }
        __syncthreads();
    }
}

// ============================================================
extern "C" void kernel_launch(void* const* d_in, const int* in_sizes, int n_in,
                              void* d_out, int out_size, void* d_ws, size_t ws_size,
                              hipStream_t stream) {
    const float* x   = (const float*)d_in[0];
    const float* g1  = (const float*)d_in[1];
    const float* be1 = (const float*)d_in[2];
    const float* w1  = (const float*)d_in[3];
    const float* b1  = (const float*)d_in[4];
    const float* w2  = (const float*)d_in[5];
    const float* b2  = (const float*)d_in[6];
    const float* emb = (const float*)d_in[7];
    const float* r   = (const float*)d_in[8];
    float* ws = (float*)d_ws;
    float* out = (float*)d_out;

    double* WD   = (double*)(ws + WS_WD);
    double* BPD  = (double*)(ws + WS_BPD);
    double* PART = (double*)(ws + WS_PART);
    int*    CNT  = (int*)(ws + WS_CNT);
    int*    WL   = (int*)(ws + WS_WL);
    unsigned short* EHI = (unsigned short*)(ws + WS_EHI);
    unsigned short* ELO = (unsigned short*)(ws + WS_ELO);

    bn_partial<<<512, 256, 0, stream>>>(x, PART);
    prep<<<65, 256, 0, stream>>>(w1, w2, b1, b2, g1, be1, emb, PART,
                                 ws + WS_WT, WD, BPD, ws + WS_BP,
                                 ws + WS_EFT, ws + WS_EN, ws + WS_E2,
                                 EHI, ELO, ws + WS_ACC, CNT);
    fused_gemm_vq<<<1536, 256, 0, stream>>>(x, ws + WS_WT, ws + WS_BP,
                                            emb, ws + WS_E2, ws + WS_EN, ws + WS_EFT,
                                            EHI, ELO, ws + WS_ACC, CNT, WL, out + 1);
    refine_fin<<<257, 256, 0, stream>>>(x, WD, BPD, emb, ws + WS_EFT, CNT, WL,
                                        out + 1, ws + WS_ACC, ws + WS_EN, r, out);
}

// Round 10
// 226.279 us; speedup vs baseline: 3.0867x; 1.1293x over previous
//
#include <hip/hip_runtime.h>
#include <math.h>

// ---------- problem constants ----------
// B=16, F=256, C=64, H=64, W=64, N_E=512. Inputs fp32, outputs fp32.
// tokens: rows r=(b*64+c)*64+h of 64 w-values; 65536 tokens total.
// fp32 GEMM -> bf16-split MFMA VQ; tokens with top-2 gap < MARGIN re-resolved in fp64.

#define CAP    2048
#define MARGIN 4e-3f

// ---------- workspace layout (float offsets) ----------
#define WS_WT   0        // [16384]   W' float [f][o]
#define WS_BP   16384    // [64]
#define WS_EN   16448    // [512]
#define WS_E2   16960    // [512]
#define WS_ACC  17472    // [8]
#define WS_CNT  17480    // [8]
#define WS_WL   17488    // [2048]
#define WS_EFT  19536    // [64*512] fp32 emb^T
#define WS_WD   52304    // [16384 dbl]
#define WS_BPD  85072    // [64 dbl]
#define WS_PART 85200    // [1024 dbl] bn partials
#define WS_EHI  87248    // [32768 ushort] emb hi bf16, XOR-swizzled granules
#define WS_ELO  103632   // [32768 ushort] emb lo bf16, swizzled

typedef __attribute__((ext_vector_type(8))) __bf16 bf16v8;
typedef __attribute__((ext_vector_type(4))) float  f32v4;

__device__ __forceinline__ unsigned short f2bf(float f) {
    union { float f; unsigned u; } v; v.f = f;
    unsigned r = v.u + 0x7FFFu + ((v.u >> 16) & 1u);
    return (unsigned short)(r >> 16);
}
__device__ __forceinline__ float bf2f(unsigned short h) {
    union { unsigned u; float f; } v; v.u = ((unsigned)h) << 16; return v.f;
}
__device__ __forceinline__ void load_lds16(const float* g, unsigned* l) {
    __builtin_amdgcn_global_load_lds((const __attribute__((address_space(1))) void*)g,
                                     (__attribute__((address_space(3))) void*)l, 16, 0, 0);
}

// ============================================================
// K1: BN partial sums (fp64). grid 512 = f*2 + chunk; chunk = 8 batches.
// ============================================================
__global__ __launch_bounds__(256) void bn_partial(
    const float* __restrict__ x, double* __restrict__ part)
{
    const int f = blockIdx.x >> 1, ch = blockIdx.x & 1, t = threadIdx.x;
    double s = 0.0, q = 0.0;
    #pragma unroll 1
    for (int bb = 0; bb < 8; ++bb) {
        const int b = ch * 8 + bb;
        const float4* p = (const float4*)(x + ((size_t)(b * 256 + f) << 12));
        #pragma unroll
        for (int ii = 0; ii < 4; ++ii) {
            float4 u = p[t + ii * 256];
            double dx = u.x, dy = u.y, dz = u.z, dw = u.w;
            s += (dx + dy) + (dz + dw);
            q = fma(dx, dx, q); q = fma(dy, dy, q);
            q = fma(dz, dz, q); q = fma(dw, dw, q);
        }
    }
    #pragma unroll
    for (int off = 32; off; off >>= 1) { s += __shfl_xor(s, off, 64); q += __shfl_xor(q, off, 64); }
    __shared__ double sh[8];
    const int wv = t >> 6;
    if ((t & 63) == 0) { sh[wv * 2] = s; sh[wv * 2 + 1] = q; }
    __syncthreads();
    if (t == 0) {
        part[blockIdx.x * 2]     = (sh[0] + sh[2]) + (sh[4] + sh[6]);
        part[blockIdx.x * 2 + 1] = (sh[1] + sh[3]) + (sh[5] + sh[7]);
    }
}

// ============================================================
// K2: prep. Blocks 0..63: a_f + W' fold (fp64) + emb transpose + bf16 hi/lo split.
//          Block 64: c_f + fused bias b' + zero accs/cnt.
// ============================================================
__global__ __launch_bounds__(256) void prep(
    const float* __restrict__ w1, const float* __restrict__ w2,
    const float* __restrict__ b1, const float* __restrict__ b2,
    const float* __restrict__ gamma, const float* __restrict__ beta,
    const float* __restrict__ emb, const double* __restrict__ part,
    float* __restrict__ Wt, double* __restrict__ Wd,
    double* __restrict__ bpd, float* __restrict__ bp,
    float* __restrict__ eft, float* __restrict__ en, float* __restrict__ e2,
    unsigned short* __restrict__ ehi, unsigned short* __restrict__ elo,
    float* __restrict__ accs, int* __restrict__ cnt)
{
    __shared__ double sh_ad[4];
    __shared__ double cdl[256];
    __shared__ double red[4][64];
    __shared__ double tsh[64];
    const int t = threadIdx.x;

    if (blockIdx.x < 64) {
        const int o = t & 63, fi = t >> 6;
        const int f = blockIdx.x * 4 + fi;
        if (o == 0) {
            double s = part[(2 * f) * 2]     + part[(2 * f + 1) * 2];
            double q = part[(2 * f) * 2 + 1] + part[(2 * f + 1) * 2 + 1];
            double mean = s * (1.0 / 65536.0);
            double var  = q * (1.0 / 65536.0) - mean * mean;
            sh_ad[fi] = (double)gamma[f] / sqrt(var + 1e-5);
        }
        __syncthreads();
        double s = 0.0;
        for (int c = 0; c < 64; ++c)
            s = fma((double)w2[o * 64 + c], (double)w1[c * 256 + f], s);
        double wp = s * sh_ad[fi];
        Wd[o * 256 + f] = wp;
        Wt[f * 64 + o]  = (float)wp;

        // embedding rows: n in [blk*8, blk*8+8); wave wv covers 2 rows; lane = k
        const int lane = t & 63, wv = t >> 6;
        #pragma unroll
        for (int rr = 0; rr < 2; ++rr) {
            int n = blockIdx.x * 8 + rr * 4 + wv;
            float v = emb[n * 64 + lane];
            eft[lane * 512 + n] = v;
            unsigned short hb = f2bf(v);
            unsigned short lb = f2bf(v - bf2f(hb));
            int pos = (lane >> 3) ^ (n & 7);          // XOR-swizzled granule
            ehi[n * 64 + pos * 8 + (lane & 7)] = hb;
            elo[n * 64 + pos * 8 + (lane & 7)] = lb;
            float qq = v * v;
            #pragma unroll
            for (int off = 32; off; off >>= 1) qq += __shfl_xor(qq, off, 64);
            if (lane == 0) { e2[n] = qq; en[n] = sqrtf(qq); }
        }
    } else {
        {
            const int f = t;
            double s = part[(2 * f) * 2]     + part[(2 * f + 1) * 2];
            double q = part[(2 * f) * 2 + 1] + part[(2 * f + 1) * 2 + 1];
            double mean = s * (1.0 / 65536.0);
            double var  = q * (1.0 / 65536.0) - mean * mean;
            double a = (double)gamma[f] / sqrt(var + 1e-5);
            cdl[f] = (double)beta[f] - mean * a;
        }
        __syncthreads();
        const int o = t & 63, p = t >> 6;
        double ss = 0.0;
        for (int j = 0; j < 64; ++j) {
            int fidx = p * 64 + j;
            ss = fma((double)w1[o * 256 + fidx], cdl[fidx], ss);
        }
        red[p][o] = ss; __syncthreads();
        if (t < 64) tsh[t] = (double)b1[t] + (red[0][t] + red[1][t]) + (red[2][t] + red[3][t]);
        __syncthreads();
        if (t < 64) {
            double bb = (double)b2[t];
            for (int c = 0; c < 64; ++c)
                bb = fma((double)w2[t * 64 + c], tsh[c], bb);
            bpd[t] = bb;
            bp[t]  = (float)bb;
        }
        if (t < 8) accs[t] = 0.f;
        if (t == 0) cnt[0] = 0;
    }
}

// ============================================================
// K3: blocks 0..1023: fused GEMM (fp32 VALU) + VQ (bf16-split MFMA) per (b,h).
//     blocks 1024..1535: codebook angular stats.
// Round-10 change: ONE 16.6KB LDS arena reused 3x (fp32 z -> bf16 z hi/lo ->
// VQ staging double-buffer) + serialized 4-step reduction. LDS 37.4->20.7KB
// so ~6 blocks/CU can be resident (was ~2: Occupancy 22%, VALUBusy 29% --
// stall-bound, issue floor is only ~20us of the 124us). Also 16-deep x
// prefetch and batched z_q gather.
// ============================================================
__global__ __launch_bounds__(256, 2) void fused_gemm_vq(
    const float* __restrict__ x,
    const float* __restrict__ Wt,
    const float* __restrict__ bp,
    const float* __restrict__ emb,
    const float* __restrict__ e2,
    const float* __restrict__ en,
    const float* __restrict__ eft,
    const unsigned short* __restrict__ ehi,
    const unsigned short* __restrict__ elo,
    float* __restrict__ accs,
    int* __restrict__ cnt, int* __restrict__ wl,
    float* __restrict__ zq)
{
    __shared__ __align__(16) unsigned smem[5184];
    enum { OR = 0,            // 4160-word arena: z fp32 (stride 65) -> zhi[0,2048)+zlo[2048,4096) -> staging buf0/buf1
           OE2 = 4160, OZ2 = 4672, OPRT = 4736, ODT = 4992, OD2T = 5056, OIT = 5120 };
    float* zsA = (float*)(smem + OR);
    float* e2s = (float*)(smem + OE2);
    float* z2s = (float*)(smem + OZ2);
    float* prt = (float*)(smem + OPRT);
    float* dT  = (float*)(smem + ODT);
    float* d2T = (float*)(smem + OD2T);
    int*   iT  = (int*)(smem + OIT);

    const int tid = threadIdx.x, lane = tid & 63, wv = tid >> 6;

    // ---------------- codebook-stats blocks ----------------
    if (blockIdx.x >= 1024) {
        const int i = blockIdx.x - 1024;
        float* ang = e2s;                   // 512 floats
        const float eni = en[i];
        const float* ei = emb + (i << 6);
        #pragma unroll
        for (int jj = 0; jj < 2; ++jj) {
            const int j = tid + jj * 256;
            float d0 = 0.f, d1 = 0.f, d2 = 0.f, d3 = 0.f;
            #pragma unroll
            for (int k = 0; k < 64; k += 4) {
                d0 = fmaf(ei[k + 0], eft[(k + 0) * 512 + j], d0);
                d1 = fmaf(ei[k + 1], eft[(k + 1) * 512 + j], d1);
                d2 = fmaf(ei[k + 2], eft[(k + 2) * 512 + j], d2);
                d3 = fmaf(ei[k + 3], eft[(k + 3) * 512 + j], d3);
            }
            float dot = (d0 + d1) + (d2 + d3);
            float xv = dot / (eni * en[j]);
            xv = fminf(fmaxf(xv, -0.99999f), 0.99999f);
            ang[j] = acosf(xv);
        }
        __syncthreads();
        if (wv == 0) {
            float m1 = 3.4e38f, m2 = 3.4e38f, ssum = 0.f;
            #pragma unroll
            for (int t8 = 0; t8 < 8; ++t8) {
                float a = ang[t8 * 64 + lane];
                ssum += a;
                if (a < m1) { m2 = m1; m1 = a; }
                else if (a < m2) m2 = a;
            }
            #pragma unroll
            for (int off = 32; off; off >>= 1) ssum += __shfl_xor(ssum, off, 64);
            #pragma unroll
            for (int off = 32; off; off >>= 1) {
                float o1 = __shfl_xor(m1, off, 64);
                float o2 = __shfl_xor(m2, off, 64);
                if (o1 < m1) { m2 = fminf(m1, o2); m1 = o1; }
                else          m2 = fminf(m2, o1);
            }
            float mean = ssum * (1.f / 512.f);
            float vs = 0.f;
            #pragma unroll
            for (int t8 = 0; t8 < 8; ++t8) {
                float tt = ang[t8 * 64 + lane] - mean;
                vs = fmaf(tt, tt, vs);
            }
            #pragma unroll
            for (int off = 32; off; off >>= 1) vs += __shfl_xor(vs, off, 64);
            if (lane == 0) {
                atomicAdd(accs + 1, vs * (1.f / 511.f));
                atomicAdd(accs + 2, m2);
            }
        }
        return;
    }

    // ---------------- main GEMM+VQ blocks ----------------
    const int wvu = __builtin_amdgcn_readfirstlane(wv);
    const int b = blockIdx.x >> 6, h = blockIdx.x & 63;

    // e2 -> LDS
    e2s[tid]       = e2[tid];
    e2s[tid + 256] = e2[tid + 256];

    // ---- fp32 GEMM: wave wv accumulates features [wv*64,(wv+1)*64) ----
    float acc[64];
    #pragma unroll
    for (int c = 0; c < 64; ++c) acc[c] = 0.f;
    const float* xb = x + ((size_t)(b * 256 + wvu * 64) << 12) + (h << 6) + lane;
    const float* wp = Wt + wvu * 64 * 64;
    float xcur[16], xnxt[16];
    #pragma unroll
    for (int j = 0; j < 16; ++j) xcur[j] = xb[(size_t)j << 12];
    #pragma unroll 1
    for (int ib = 0; ib < 4; ++ib) {
        if (ib < 3) {
            #pragma unroll
            for (int j = 0; j < 16; ++j) xnxt[j] = xb[(size_t)((ib + 1) * 16 + j) << 12];
        }
        #pragma unroll
        for (int j = 0; j < 16; ++j) {
            const float* wrow = wp + (ib * 16 + j) * 64;
            #pragma unroll
            for (int c = 0; c < 64; ++c)
                acc[c] = fmaf(wrow[c], xcur[j], acc[c]);
        }
        if (ib < 3) {
            #pragma unroll
            for (int j = 0; j < 16; ++j) xcur[j] = xnxt[j];
        }
    }

    // ---- serialized 4-step reduction into the single arena ----
    if (wv == 0) {
        #pragma unroll
        for (int c = 0; c < 64; ++c) zsA[c * 65 + lane] = acc[c] + bp[c];
    }
    __syncthreads();
    if (wv == 1) {
        #pragma unroll
        for (int c = 0; c < 64; ++c) zsA[c * 65 + lane] += acc[c];
    }
    __syncthreads();
    if (wv == 2) {
        #pragma unroll
        for (int c = 0; c < 64; ++c) zsA[c * 65 + lane] += acc[c];
    }
    __syncthreads();
    if (wv == 3) {
        #pragma unroll
        for (int c = 0; c < 64; ++c) zsA[c * 65 + lane] += acc[c];
    }
    __syncthreads();

    // ---- read own z slice, then overwrite arena with bf16 hi/lo ----
    const int k0 = wvu * 16;     // this wave's k-range; token = lane
    float zv[16];
    #pragma unroll
    for (int j = 0; j < 16; ++j) zv[j] = zsA[lane * 65 + k0 + j];
    {
        float p2 = 0.f;
        #pragma unroll
        for (int j = 0; j < 16; ++j) p2 = fmaf(zv[j], zv[j], p2);
        prt[wvu * 64 + lane] = p2;
    }
    __syncthreads();             // all zsA reads done -> arena reusable
    #pragma unroll
    for (int w2 = 0; w2 < 8; ++w2) {
        int k = k0 + 2 * w2;
        unsigned short h0 = f2bf(zv[2 * w2]), h1 = f2bf(zv[2 * w2 + 1]);
        unsigned short l0 = f2bf(zv[2 * w2] - bf2f(h0));
        unsigned short l1 = f2bf(zv[2 * w2 + 1] - bf2f(h1));
        int pos = (k >> 3) ^ (lane & 7);
        int widx = lane * 32 + pos * 4 + ((k & 7) >> 1);
        smem[OR + widx]        = (unsigned)h0 | ((unsigned)h1 << 16);
        smem[OR + 2048 + widx] = (unsigned)l0 | ((unsigned)l1 << 16);
    }
    __syncthreads();             // zhi/zlo ready

    // A-fragments to registers; z2 totals
    const int cq = lane & 15, qd = lane >> 4;
    const int x7 = cq & 7;
    bf16v8 ahi[2], alo[2];
    {
        const int rbase = (wvu * 16 + cq) * 32;
        #pragma unroll
        for (int s = 0; s < 2; ++s) {
            int pos = ((s * 4 + qd) ^ x7) * 4;
            ahi[s] = *(const bf16v8*)(smem + OR + rbase + pos);
            alo[s] = *(const bf16v8*)(smem + OR + 2048 + rbase + pos);
        }
    }
    if (wvu == 0)
        z2s[lane] = (prt[lane] + prt[64 + lane]) + (prt[128 + lane] + prt[192 + lane]);
    __syncthreads();             // A-frag reads done -> arena becomes staging

    if (wvu == 0) {              // stage tiles 0,1 (32 codes each, hi+lo)
        const float* gh = (const float*)ehi;
        const float* gl = (const float*)elo;
        #pragma unroll
        for (int j = 0; j < 4; ++j) load_lds16(gh + j * 256 + lane * 4, smem + OR + j * 256);
        #pragma unroll
        for (int j = 0; j < 4; ++j) load_lds16(gl + j * 256 + lane * 4, smem + OR + 1024 + j * 256);
        gh += 1024; gl += 1024;
        #pragma unroll
        for (int j = 0; j < 4; ++j) load_lds16(gh + j * 256 + lane * 4, smem + OR + 2048 + j * 256);
        #pragma unroll
        for (int j = 0; j < 4; ++j) load_lds16(gl + j * 256 + lane * 4, smem + OR + 3072 + j * 256);
    }

    float z2r[4];
    float m1[4] = {3.4e38f, 3.4e38f, 3.4e38f, 3.4e38f};
    float m2[4] = {3.4e38f, 3.4e38f, 3.4e38f, 3.4e38f};
    int   i1[4] = {0, 0, 0, 0};
    const int p0 = (qd ^ x7) * 4, p1 = ((4 + qd) ^ x7) * 4;

    #pragma unroll 1
    for (int t2 = 0; t2 < 32; ++t2) {
        if ((t2 & 1) == 0) {
            __syncthreads();                       // staged tile (t2>>1) ready
            int st = t2 >> 1;
            if (wvu == 0 && st < 15) {             // prefetch next tile
                const float* gh = (const float*)ehi + (size_t)(st + 1) * 1024;
                const float* gl = (const float*)elo + (size_t)(st + 1) * 1024;
                unsigned* dst = smem + OR + ((st + 1) & 1) * 2048;
                #pragma unroll
                for (int j = 0; j < 4; ++j) load_lds16(gh + j * 256 + lane * 4, dst + j * 256);
                #pragma unroll
                for (int j = 0; j < 4; ++j) load_lds16(gl + j * 256 + lane * 4, dst + 1024 + j * 256);
            }
            if (t2 == 0) {
                #pragma unroll
                for (int r = 0; r < 4; ++r) z2r[r] = z2s[wvu * 16 + qd * 4 + r];
            }
        }
        const int rb = OR + ((t2 >> 1) & 1) * 2048 + ((t2 & 1) * 16 + cq) * 32;
        bf16v8 bh0 = *(const bf16v8*)(smem + rb + p0);
        bf16v8 bh1 = *(const bf16v8*)(smem + rb + p1);
        bf16v8 bl0 = *(const bf16v8*)(smem + rb + 1024 + p0);
        bf16v8 bl1 = *(const bf16v8*)(smem + rb + 1024 + p1);
        f32v4 a0 = {0.f, 0.f, 0.f, 0.f}, a1 = {0.f, 0.f, 0.f, 0.f};
        a0 = __builtin_amdgcn_mfma_f32_16x16x32_bf16(ahi[0], bh0, a0, 0, 0, 0);
        a1 = __builtin_amdgcn_mfma_f32_16x16x32_bf16(ahi[1], bh1, a1, 0, 0, 0);
        a0 = __builtin_amdgcn_mfma_f32_16x16x32_bf16(ahi[0], bl0, a0, 0, 0, 0);
        a1 = __builtin_amdgcn_mfma_f32_16x16x32_bf16(ahi[1], bl1, a1, 0, 0, 0);
        a0 = __builtin_amdgcn_mfma_f32_16x16x32_bf16(alo[0], bh0, a0, 0, 0, 0);
        a1 = __builtin_amdgcn_mfma_f32_16x16x32_bf16(alo[1], bh1, a1, 0, 0, 0);
        a0 = __builtin_amdgcn_mfma_f32_16x16x32_bf16(alo[0], bl0, a0, 0, 0, 0);
        a1 = __builtin_amdgcn_mfma_f32_16x16x32_bf16(alo[1], bl1, a1, 0, 0, 0);
        const float eps = e2s[t2 * 16 + cq];
        const int n = t2 * 16 + cq;
        #pragma unroll
        for (int r = 0; r < 4; ++r) {
            float d = fmaf(-2.f, a0[r] + a1[r], z2r[r] + eps);
            if (d < m1[r])      { m2[r] = m1[r]; m1[r] = d; i1[r] = n; }
            else if (d < m2[r]) { m2[r] = d; }
        }
    }

    // merge top-2 across the 16 columns of each lane group (tokens identical)
    #pragma unroll
    for (int r = 0; r < 4; ++r) {
        #pragma unroll
        for (int off = 1; off <= 8; off <<= 1) {
            float o1 = __shfl_xor(m1[r], off, 64);
            float o2 = __shfl_xor(m2[r], off, 64);
            int   oi = __shfl_xor(i1[r], off, 64);
            if (o1 < m1[r] || (o1 == m1[r] && oi < i1[r])) {
                m2[r] = fminf(m1[r], o2); m1[r] = o1; i1[r] = oi;
            } else {
                m2[r] = fminf(m2[r], o1);
            }
        }
    }
    if (cq == 0) {
        #pragma unroll
        for (int r = 0; r < 4; ++r) {
            int tok = wvu * 16 + qd * 4 + r;
            dT[tok] = m1[r]; d2T[tok] = m2[r]; iT[tok] = i1[r];
        }
    }
    __syncthreads();

    if (wv == 0) {
        float mm1 = dT[lane], mm2 = d2T[lane];
        if (mm2 - mm1 < MARGIN) {               // near-tie -> fp64 refine
            int pos = atomicAdd(cnt, 1);
            if (pos < CAP) wl[pos] = ((b << 6) + lane) * 64 + h;
        }
        float ms = mm1;
        #pragma unroll
        for (int off = 32; off; off >>= 1) ms += __shfl_xor(ms, off, 64);
        if (lane == 0) atomicAdd(accs + 0, ms);
    }
    __syncthreads();

    // z_q write: wave wv writes channels [wv*16,(wv+1)*16); batched gather
    float* zrow = zq + ((size_t)(b * 64) << 12) + (h << 6) + lane;
    #pragma unroll
    for (int cc = 0; cc < 16; ++cc) {
        int c = wvu * 16 + cc;
        int id = iT[c];
        zrow[(size_t)c << 12] = emb[(id << 6) + lane];
    }
}

// ============================================================
// K4: fp64 refinement (blocks 0..255, persistent) + finalize (block 256)
// ============================================================
__global__ __launch_bounds__(256) void refine_fin(
    const float* __restrict__ x,
    const double* __restrict__ Wd,
    const double* __restrict__ bpd,
    const float* __restrict__ emb,
    const float* __restrict__ eft,
    const int* __restrict__ cnt, const int* __restrict__ wl,
    float* __restrict__ zq,
    const float* __restrict__ accs, const float* __restrict__ en,
    const float* __restrict__ r, float* __restrict__ out)
{
    const int tid = threadIdx.x, lane = tid & 63, wv = tid >> 6;

    if (blockIdx.x == 256) {
        if (wv == 0) {
            float hs = 0.f, rs = 0.f;
            #pragma unroll
            for (int jj = 0; jj < 8; ++jj) {
                int n = (jj << 6) + lane;
                float rv = r[n];
                float d = rv - en[n];
                hs = fmaf(d, d, hs);
                rs += fminf(fmaxf(rv, 0.9f), 1.1f);
            }
            #pragma unroll
            for (int off = 32; off; off >>= 1) { hs += __shfl_xor(hs, off, 64); rs += __shfl_xor(rs, off, 64); }
            if (lane == 0) {
                float hsw    = hs * (1.f / 512.f);
                float mean_r = rs * (1.f / 512.f);
                float mse    = accs[0] * (1.f / 4194304.f);
                float cbv    = accs[1] * (1.f / 512.f);
                float tmd    = accs[2] * (1.f / 512.f);
                float loss   = 2.f * mse + hsw + (cbv - tmd);
                out[0]       = loss;
                out[4194305] = cbv;
                out[4194306] = tmd;
                out[4194307] = hsw;
                out[4194308] = 0.f;
                out[4194309] = mean_r;
            }
        }
        return;
    }

    int count = cnt[0]; if (count > CAP) count = CAP;

    __shared__ double zp[4][64];
    __shared__ double zs[64];
    __shared__ double dsh[256];
    __shared__ int    ish[256];

    for (int it = blockIdx.x; it < count; it += 256) {
        const int r2 = wl[it];
        const int b = r2 >> 12, c = (r2 >> 6) & 63, h = r2 & 63;

        const float* xp = x + (((size_t)(b * 256 + wv * 64)) << 12) + (h << 6) + lane;
        const double* wrow = Wd + c * 256 + wv * 64;
        double zd = 0.0;
        #pragma unroll 8
        for (int f = 0; f < 64; ++f)
            zd = fma(wrow[f], (double)xp[((size_t)f) << 12], zd);
        zp[wv][lane] = zd;
        __syncthreads();
        if (tid < 64) zs[tid] = (zp[0][tid] + zp[1][tid]) + (zp[2][tid] + zp[3][tid]) + bpd[c];
        __syncthreads();

        double dm = 1e300; int im = 0;
        #pragma unroll
        for (int jj = 0; jj < 2; ++jj) {
            int n = (jj << 8) + tid;
            double d = 0.0;
            #pragma unroll 8
            for (int k = 0; k < 64; ++k) {
                double t = zs[k] - (double)eft[(k << 9) + n];
                d = fma(t, t, d);
            }
            if (d < dm) { dm = d; im = n; }
        }
        dsh[tid] = dm; ish[tid] = im;
        __syncthreads();
        for (int st = 128; st; st >>= 1) {
            if (tid < st) {
                double od = dsh[tid + st]; int oi = ish[tid + st];
                if (od < dsh[tid] || (od == dsh[tid] && oi < ish[tid])) { dsh[tid] = od; ish[tid] = oi; }
            }
            __syncthreads();
        }
        if (tid < 64) {
            int idx = ish[0];
            zq[((size_t)r2 << 6) + tid] = emb[(idx << 6) + tid];
        }
        __syncthreads();
    }
}

// ============================================================
extern "C" void kernel_launch(void* const* d_in, const int* in_sizes, int n_in,
                              void* d_out, int out_size, void* d_ws, size_t ws_size,
                              hipStream_t stream) {
    const float* x   = (const float*)d_in[0];
    const float* g1  = (const float*)d_in[1];
    const float* be1 = (const float*)d_in[2];
    const float* w1  = (const float*)d_in[3];
    const float* b1  = (const float*)d_in[4];
    const float* w2  = (const float*)d_in[5];
    const float* b2  = (const float*)d_in[6];
    const float* emb = (const float*)d_in[7];
    const float* r   = (const float*)d_in[8];
    float* ws = (float*)d_ws;
    float* out = (float*)d_out;

    double* WD   = (double*)(ws + WS_WD);
    double* BPD  = (double*)(ws + WS_BPD);
    double* PART = (double*)(ws + WS_PART);
    int*    CNT  = (int*)(ws + WS_CNT);
    int*    WL   = (int*)(ws + WS_WL);
    unsigned short* EHI = (unsigned short*)(ws + WS_EHI);
    unsigned short* ELO = (unsigned short*)(ws + WS_ELO);

    bn_partial<<<512, 256, 0, stream>>>(x, PART);
    prep<<<65, 256, 0, stream>>>(w1, w2, b1, b2, g1, be1, emb, PART,
                                 ws + WS_WT, WD, BPD, ws + WS_BP,
                                 ws + WS_EFT, ws + WS_EN, ws + WS_E2,
                                 EHI, ELO, ws + WS_ACC, CNT);
    fused_gemm_vq<<<1536, 256, 0, stream>>>(x, ws + WS_WT, ws + WS_BP,
                                            emb, ws + WS_E2, ws + WS_EN, ws + WS_EFT,
                                            EHI, ELO, ws + WS_ACC, CNT, WL, out + 1);
    refine_fin<<<257, 256, 0, stream>>>(x, WD, BPD, emb, ws + WS_EFT, CNT, WL,
                                        out + 1, ws + WS_ACC, ws + WS_EN, r, out);
}

// Round 11
// 196.155 us; speedup vs baseline: 3.5608x; 1.1536x over previous
//
#include <hip/hip_runtime.h>
#include <math.h>

// ---------- problem constants ----------
// B=16, F=256, C=64, H=64, W=64, N_E=512. Inputs fp32, outputs fp32.
// tokens: rows r=(b*64+c)*64+h of 64 w-values; 65536 tokens total.
// bf16-split MFMA GEMM + bf16-split MFMA VQ; near-ties re-resolved in fp64.

#define CAP    2048
#define MARGIN 4e-3f

// ---------- workspace layout (float offsets) ----------
#define WS_WHI  0        // [16384 ushort] W' hi bf16, A-frag order ((mt*8+s)*64+lane)*8+j
#define WS_WLO  8192     // [16384 ushort] W' lo bf16
#define WS_BP   16384    // [64]
#define WS_EN   16448    // [512]
#define WS_E2   16960    // [512]
#define WS_ACC  17472    // [8]
#define WS_CNT  17480    // [8]
#define WS_WL   17488    // [2048]
#define WS_EFT  19536    // [64*512] fp32 emb^T
#define WS_WD   52304    // [16384 dbl]
#define WS_BPD  85072    // [64 dbl]
#define WS_PART 85200    // [1024 dbl] bn partials
#define WS_EHI  87248    // [32768 ushort] emb hi bf16, XOR-swizzled granules
#define WS_ELO  103632   // [32768 ushort] emb lo bf16, swizzled

typedef __attribute__((ext_vector_type(8))) __bf16 bf16v8;
typedef __attribute__((ext_vector_type(4))) float  f32v4;

__device__ __forceinline__ unsigned short f2bf(float f) {
    union { float f; unsigned u; } v; v.f = f;
    unsigned r = v.u + 0x7FFFu + ((v.u >> 16) & 1u);
    return (unsigned short)(r >> 16);
}
__device__ __forceinline__ float bf2f(unsigned short h) {
    union { unsigned u; float f; } v; v.u = ((unsigned)h) << 16; return v.f;
}
__device__ __forceinline__ void load_lds16(const float* g, unsigned* l) {
    __builtin_amdgcn_global_load_lds((const __attribute__((address_space(1))) void*)g,
                                     (__attribute__((address_space(3))) void*)l, 16, 0, 0);
}

// ============================================================
// K1: BN partial sums (fp64). grid 512 = f*2 + chunk; chunk = 8 batches.
// ============================================================
__global__ __launch_bounds__(256) void bn_partial(
    const float* __restrict__ x, double* __restrict__ part)
{
    const int f = blockIdx.x >> 1, ch = blockIdx.x & 1, t = threadIdx.x;
    double s = 0.0, q = 0.0;
    #pragma unroll 1
    for (int bb = 0; bb < 8; ++bb) {
        const int b = ch * 8 + bb;
        const float4* p = (const float4*)(x + ((size_t)(b * 256 + f) << 12));
        #pragma unroll
        for (int ii = 0; ii < 4; ++ii) {
            float4 u = p[t + ii * 256];
            double dx = u.x, dy = u.y, dz = u.z, dw = u.w;
            s += (dx + dy) + (dz + dw);
            q = fma(dx, dx, q); q = fma(dy, dy, q);
            q = fma(dz, dz, q); q = fma(dw, dw, q);
        }
    }
    #pragma unroll
    for (int off = 32; off; off >>= 1) { s += __shfl_xor(s, off, 64); q += __shfl_xor(q, off, 64); }
    __shared__ double sh[8];
    const int wv = t >> 6;
    if ((t & 63) == 0) { sh[wv * 2] = s; sh[wv * 2 + 1] = q; }
    __syncthreads();
    if (t == 0) {
        part[blockIdx.x * 2]     = (sh[0] + sh[2]) + (sh[4] + sh[6]);
        part[blockIdx.x * 2 + 1] = (sh[1] + sh[3]) + (sh[5] + sh[7]);
    }
}

// ============================================================
// K2: prep. Blocks 0..63: a_f + W' fold (fp64) + W' bf16 hi/lo A-frag split
//      + emb transpose + emb bf16 split. Block 64: c_f + bias + zero accs.
// ============================================================
__global__ __launch_bounds__(256) void prep(
    const float* __restrict__ w1, const float* __restrict__ w2,
    const float* __restrict__ b1, const float* __restrict__ b2,
    const float* __restrict__ gamma, const float* __restrict__ beta,
    const float* __restrict__ emb, const double* __restrict__ part,
    unsigned short* __restrict__ whi, unsigned short* __restrict__ wlo,
    double* __restrict__ Wd,
    double* __restrict__ bpd, float* __restrict__ bp,
    float* __restrict__ eft, float* __restrict__ en, float* __restrict__ e2,
    unsigned short* __restrict__ ehi, unsigned short* __restrict__ elo,
    float* __restrict__ accs, int* __restrict__ cnt)
{
    __shared__ double sh_ad[4];
    __shared__ double cdl[256];
    __shared__ double red[4][64];
    __shared__ double tsh[64];
    const int t = threadIdx.x;

    if (blockIdx.x < 64) {
        const int o = t & 63, fi = t >> 6;
        const int f = blockIdx.x * 4 + fi;
        if (o == 0) {
            double s = part[(2 * f) * 2]     + part[(2 * f + 1) * 2];
            double q = part[(2 * f) * 2 + 1] + part[(2 * f + 1) * 2 + 1];
            double mean = s * (1.0 / 65536.0);
            double var  = q * (1.0 / 65536.0) - mean * mean;
            sh_ad[fi] = (double)gamma[f] / sqrt(var + 1e-5);
        }
        __syncthreads();
        double s = 0.0;
        for (int c = 0; c < 64; ++c)
            s = fma((double)w2[o * 64 + c], (double)w1[c * 256 + f], s);
        double wp = s * sh_ad[fi];
        Wd[o * 256 + f] = wp;
        // bf16 hi/lo split in A-frag order: element (m=c=o, k=f)
        {
            float wpf = (float)wp;
            unsigned short wh = f2bf(wpf);
            unsigned short wlv = f2bf(wpf - bf2f(wh));
            int mt = o >> 4, cq_ = o & 15, sK = f >> 5, qd_ = (f >> 3) & 3, j = f & 7;
            int idx = ((mt * 8 + sK) * 64 + qd_ * 16 + cq_) * 8 + j;
            whi[idx] = wh; wlo[idx] = wlv;
        }

        // embedding rows: n in [blk*8, blk*8+8); wave wv covers 2 rows; lane = k
        const int lane = t & 63, wv = t >> 6;
        #pragma unroll
        for (int rr = 0; rr < 2; ++rr) {
            int n = blockIdx.x * 8 + rr * 4 + wv;
            float v = emb[n * 64 + lane];
            eft[lane * 512 + n] = v;
            unsigned short hb = f2bf(v);
            unsigned short lb = f2bf(v - bf2f(hb));
            int pos = (lane >> 3) ^ (n & 7);          // XOR-swizzled granule
            ehi[n * 64 + pos * 8 + (lane & 7)] = hb;
            elo[n * 64 + pos * 8 + (lane & 7)] = lb;
            float qq = v * v;
            #pragma unroll
            for (int off = 32; off; off >>= 1) qq += __shfl_xor(qq, off, 64);
            if (lane == 0) { e2[n] = qq; en[n] = sqrtf(qq); }
        }
    } else {
        {
            const int f = t;
            double s = part[(2 * f) * 2]     + part[(2 * f + 1) * 2];
            double q = part[(2 * f) * 2 + 1] + part[(2 * f + 1) * 2 + 1];
            double mean = s * (1.0 / 65536.0);
            double var  = q * (1.0 / 65536.0) - mean * mean;
            double a = (double)gamma[f] / sqrt(var + 1e-5);
            cdl[f] = (double)beta[f] - mean * a;
        }
        __syncthreads();
        const int o = t & 63, p = t >> 6;
        double ss = 0.0;
        for (int j = 0; j < 64; ++j) {
            int fidx = p * 64 + j;
            ss = fma((double)w1[o * 256 + fidx], cdl[fidx], ss);
        }
        red[p][o] = ss; __syncthreads();
        if (t < 64) tsh[t] = (double)b1[t] + (red[0][t] + red[1][t]) + (red[2][t] + red[3][t]);
        __syncthreads();
        if (t < 64) {
            double bb = (double)b2[t];
            for (int c = 0; c < 64; ++c)
                bb = fma((double)w2[t * 64 + c], tsh[c], bb);
            bpd[t] = bb;
            bp[t]  = (float)bb;
        }
        if (t < 8) accs[t] = 0.f;
        if (t == 0) cnt[0] = 0;
    }
}

// ============================================================
// K3: blocks 0..1023: MFMA GEMM + MFMA VQ per (b,h); 1024..1535: cb stats.
// GEMM: A=W' bf16 hi/lo frags from global (coalesced); B=x loaded to regs
// (16/chunk/wave, next chunk prefetched during MFMA), runtime bf16-split,
// staged in XOR-swizzled LDS. Wave owns full-K M-tile -> NO cross-wave
// reduction (r10's 4-step serial reduction eliminated). 3-term split
// (hi*hi+hi*lo+lo*hi). z exits in C-layout -> bias+z2 via shuffle ->
// XOR arena -> VQ path identical to r10.
// ============================================================
__global__ __launch_bounds__(256, 2) void fused_gemm_vq(
    const float* __restrict__ x,
    const unsigned short* __restrict__ whi,
    const unsigned short* __restrict__ wlo,
    const float* __restrict__ bp,
    const float* __restrict__ emb,
    const float* __restrict__ e2,
    const float* __restrict__ en,
    const float* __restrict__ eft,
    const unsigned short* __restrict__ ehi,
    const unsigned short* __restrict__ elo,
    float* __restrict__ accs,
    int* __restrict__ cnt, int* __restrict__ wl,
    float* __restrict__ zq)
{
    __shared__ __align__(16) unsigned smem[4880];
    enum { OAR = 0,   // [0,4096): XB hi/lo during GEMM -> z hi/lo -> VQ staging
           OE2 = 4096, OZ2 = 4608, ODT = 4672, OD2T = 4736, OIT = 4800 };
    float* e2s = (float*)(smem + OE2);
    float* z2s = (float*)(smem + OZ2);
    float* dT  = (float*)(smem + ODT);
    float* d2T = (float*)(smem + OD2T);
    int*   iT  = (int*)(smem + OIT);

    const int tid = threadIdx.x, lane = tid & 63, wv = tid >> 6;

    // ---------------- codebook-stats blocks ----------------
    if (blockIdx.x >= 1024) {
        const int i = blockIdx.x - 1024;
        float* ang = e2s;
        const float eni = en[i];
        const float* ei = emb + (i << 6);
        #pragma unroll
        for (int jj = 0; jj < 2; ++jj) {
            const int j = tid + jj * 256;
            float d0 = 0.f, d1 = 0.f, d2 = 0.f, d3 = 0.f;
            #pragma unroll
            for (int k = 0; k < 64; k += 4) {
                d0 = fmaf(ei[k + 0], eft[(k + 0) * 512 + j], d0);
                d1 = fmaf(ei[k + 1], eft[(k + 1) * 512 + j], d1);
                d2 = fmaf(ei[k + 2], eft[(k + 2) * 512 + j], d2);
                d3 = fmaf(ei[k + 3], eft[(k + 3) * 512 + j], d3);
            }
            float dot = (d0 + d1) + (d2 + d3);
            float xv = dot / (eni * en[j]);
            xv = fminf(fmaxf(xv, -0.99999f), 0.99999f);
            ang[j] = acosf(xv);
        }
        __syncthreads();
        if (wv == 0) {
            float m1 = 3.4e38f, m2 = 3.4e38f, ssum = 0.f;
            #pragma unroll
            for (int t8 = 0; t8 < 8; ++t8) {
                float a = ang[t8 * 64 + lane];
                ssum += a;
                if (a < m1) { m2 = m1; m1 = a; }
                else if (a < m2) m2 = a;
            }
            #pragma unroll
            for (int off = 32; off; off >>= 1) ssum += __shfl_xor(ssum, off, 64);
            #pragma unroll
            for (int off = 32; off; off >>= 1) {
                float o1 = __shfl_xor(m1, off, 64);
                float o2 = __shfl_xor(m2, off, 64);
                if (o1 < m1) { m2 = fminf(m1, o2); m1 = o1; }
                else          m2 = fminf(m2, o1);
            }
            float mean = ssum * (1.f / 512.f);
            float vs = 0.f;
            #pragma unroll
            for (int t8 = 0; t8 < 8; ++t8) {
                float tt = ang[t8 * 64 + lane] - mean;
                vs = fmaf(tt, tt, vs);
            }
            #pragma unroll
            for (int off = 32; off; off >>= 1) vs += __shfl_xor(vs, off, 64);
            if (lane == 0) {
                atomicAdd(accs + 1, vs * (1.f / 511.f));
                atomicAdd(accs + 2, m2);
            }
        }
        return;
    }

    // ---------------- main GEMM+VQ blocks ----------------
    const int wvu = __builtin_amdgcn_readfirstlane(wv);
    const int b = blockIdx.x >> 6, h = blockIdx.x & 63;
    const int cq = lane & 15, qd = lane >> 4;

    // A-frags (W' hi/lo), coalesced global b128 loads
    bf16v8 Ahi[8], Alo[8];
    #pragma unroll
    for (int s = 0; s < 8; ++s) {
        Ahi[s] = *(const bf16v8*)(whi + ((size_t)((wvu * 8 + s) * 64 + lane)) * 8);
        Alo[s] = *(const bf16v8*)(wlo + ((size_t)((wvu * 8 + s) * 64 + lane)) * 8);
    }
    // e2 -> LDS
    e2s[tid]       = e2[tid];
    e2s[tid + 256] = e2[tid + 256];

    // x chunk 0 into regs: wave wvu covers chunk-f = wvu*16 + i; w = lane
    const float* xb = x + ((size_t)(b * 256 + wvu * 16) << 12) + (h << 6) + lane;
    float xv[16];
    #pragma unroll
    for (int i = 0; i < 16; ++i) xv[i] = xb[(size_t)i << 12];

    f32v4 acc[4];
    #pragma unroll
    for (int nt = 0; nt < 4; ++nt) acc[nt] = (f32v4){0.f, 0.f, 0.f, 0.f};

    #pragma unroll
    for (int chk = 0; chk < 4; ++chk) {
        __syncthreads();                           // XB free
        // bf16-split xv -> XB (XOR-swizzled granules; rows = w, 8 granules)
        #pragma unroll
        for (int p = 0; p < 8; ++p) {
            const int i = 2 * p;
            unsigned short h0 = f2bf(xv[i]),     h1 = f2bf(xv[i + 1]);
            unsigned short l0 = f2bf(xv[i] - bf2f(h0));
            unsigned short l1 = f2bf(xv[i + 1] - bf2f(h1));
            const int g = 2 * wvu + (p >> 2);
            const int widx = lane * 32 + ((g ^ (lane & 7)) << 2) + (p & 3);
            smem[OAR + widx]        = (unsigned)h0 | ((unsigned)h1 << 16);
            smem[OAR + 2048 + widx] = (unsigned)l0 | ((unsigned)l1 << 16);
        }
        __syncthreads();                           // XB ready
        if (chk < 3) {                             // prefetch next chunk into regs
            const float* xb2 = xb + ((size_t)((chk + 1) * 64) << 12);
            #pragma unroll
            for (int i = 0; i < 16; ++i) xv[i] = xb2[(size_t)i << 12];
        }
        #pragma unroll
        for (int st2 = 0; st2 < 2; ++st2) {
            const int s = chk * 2 + st2;
            #pragma unroll
            for (int nt = 0; nt < 4; ++nt) {
                const int row = nt * 16 + cq;
                const int pos = row * 32 + (((st2 * 4 + qd) ^ (row & 7)) << 2);
                bf16v8 bh = *(const bf16v8*)(smem + OAR + pos);
                bf16v8 bl = *(const bf16v8*)(smem + OAR + 2048 + pos);
                acc[nt] = __builtin_amdgcn_mfma_f32_16x16x32_bf16(Ahi[s], bh, acc[nt], 0, 0, 0);
                acc[nt] = __builtin_amdgcn_mfma_f32_16x16x32_bf16(Ahi[s], bl, acc[nt], 0, 0, 0);
                acc[nt] = __builtin_amdgcn_mfma_f32_16x16x32_bf16(Alo[s], bh, acc[nt], 0, 0, 0);
            }
        }
    }
    __syncthreads();                               // last MFMA reads done

    // bias + z2 + write z hi/lo into arena (C-layout: c=qd*4+r, w=nt*16+cq)
    float zvr[4][4];
    {
        float bpv[4];
        #pragma unroll
        for (int r = 0; r < 4; ++r) bpv[r] = bp[wvu * 16 + qd * 4 + r];
        #pragma unroll
        for (int nt = 0; nt < 4; ++nt)
            #pragma unroll
            for (int r = 0; r < 4; ++r) zvr[nt][r] = acc[nt][r] + bpv[r];
        float z2p[4];
        #pragma unroll
        for (int r = 0; r < 4; ++r) {
            float p2 = 0.f;
            #pragma unroll
            for (int nt = 0; nt < 4; ++nt) p2 = fmaf(zvr[nt][r], zvr[nt][r], p2);
            #pragma unroll
            for (int off = 1; off <= 8; off <<= 1) p2 += __shfl_xor(p2, off, 64);
            z2p[r] = p2;
        }
        if (cq == 0) {
            #pragma unroll
            for (int r = 0; r < 4; ++r) z2s[wvu * 16 + qd * 4 + r] = z2p[r];
        }
        unsigned short* ar = (unsigned short*)(smem + OAR);
        #pragma unroll
        for (int nt = 0; nt < 4; ++nt) {
            const int w = nt * 16 + cq;
            const int gz = w >> 3, kj = w & 7;
            #pragma unroll
            for (int r = 0; r < 4; ++r) {
                const int tok = wvu * 16 + qd * 4 + r;
                const int hw = tok * 64 + ((gz ^ (tok & 7)) << 3) + kj;
                unsigned short zh = f2bf(zvr[nt][r]);
                ar[hw]        = zh;
                ar[4096 + hw] = f2bf(zvr[nt][r] - bf2f(zh));
            }
        }
    }
    __syncthreads();                               // z arena ready

    // VQ A-fragments to registers
    const int x7 = cq & 7;
    bf16v8 vahi[2], valo[2];
    {
        const int rbase = (wvu * 16 + cq) * 32;
        #pragma unroll
        for (int s = 0; s < 2; ++s) {
            int pos = ((s * 4 + qd) ^ x7) * 4;
            vahi[s] = *(const bf16v8*)(smem + OAR + rbase + pos);
            valo[s] = *(const bf16v8*)(smem + OAR + 2048 + rbase + pos);
        }
    }
    __syncthreads();                               // arena becomes staging

    if (wvu == 0) {                                // stage code tiles 0,1
        const float* gh = (const float*)ehi;
        const float* gl = (const float*)elo;
        #pragma unroll
        for (int j = 0; j < 4; ++j) load_lds16(gh + j * 256 + lane * 4, smem + OAR + j * 256);
        #pragma unroll
        for (int j = 0; j < 4; ++j) load_lds16(gl + j * 256 + lane * 4, smem + OAR + 1024 + j * 256);
        gh += 1024; gl += 1024;
        #pragma unroll
        for (int j = 0; j < 4; ++j) load_lds16(gh + j * 256 + lane * 4, smem + OAR + 2048 + j * 256);
        #pragma unroll
        for (int j = 0; j < 4; ++j) load_lds16(gl + j * 256 + lane * 4, smem + OAR + 3072 + j * 256);
    }

    float z2r[4];
    float m1[4] = {3.4e38f, 3.4e38f, 3.4e38f, 3.4e38f};
    float m2[4] = {3.4e38f, 3.4e38f, 3.4e38f, 3.4e38f};
    int   i1[4] = {0, 0, 0, 0};
    const int p0 = (qd ^ x7) * 4, p1 = ((4 + qd) ^ x7) * 4;

    #pragma unroll 1
    for (int t2 = 0; t2 < 32; ++t2) {
        if ((t2 & 1) == 0) {
            __syncthreads();                       // staged tile (t2>>1) ready
            int st = t2 >> 1;
            if (wvu == 0 && st < 15) {             // prefetch next tile
                const float* gh = (const float*)ehi + (size_t)(st + 1) * 1024;
                const float* gl = (const float*)elo + (size_t)(st + 1) * 1024;
                unsigned* dst = smem + OAR + ((st + 1) & 1) * 2048;
                #pragma unroll
                for (int j = 0; j < 4; ++j) load_lds16(gh + j * 256 + lane * 4, dst + j * 256);
                #pragma unroll
                for (int j = 0; j < 4; ++j) load_lds16(gl + j * 256 + lane * 4, dst + 1024 + j * 256);
            }
            if (t2 == 0) {
                #pragma unroll
                for (int r = 0; r < 4; ++r) z2r[r] = z2s[wvu * 16 + qd * 4 + r];
            }
        }
        const int rb = OAR + ((t2 >> 1) & 1) * 2048 + ((t2 & 1) * 16 + cq) * 32;
        bf16v8 bh0 = *(const bf16v8*)(smem + rb + p0);
        bf16v8 bh1 = *(const bf16v8*)(smem + rb + p1);
        bf16v8 bl0 = *(const bf16v8*)(smem + rb + 1024 + p0);
        bf16v8 bl1 = *(const bf16v8*)(smem + rb + 1024 + p1);
        f32v4 a0 = {0.f, 0.f, 0.f, 0.f}, a1 = {0.f, 0.f, 0.f, 0.f};
        a0 = __builtin_amdgcn_mfma_f32_16x16x32_bf16(vahi[0], bh0, a0, 0, 0, 0);
        a1 = __builtin_amdgcn_mfma_f32_16x16x32_bf16(vahi[1], bh1, a1, 0, 0, 0);
        a0 = __builtin_amdgcn_mfma_f32_16x16x32_bf16(vahi[0], bl0, a0, 0, 0, 0);
        a1 = __builtin_amdgcn_mfma_f32_16x16x32_bf16(vahi[1], bl1, a1, 0, 0, 0);
        a0 = __builtin_amdgcn_mfma_f32_16x16x32_bf16(valo[0], bh0, a0, 0, 0, 0);
        a1 = __builtin_amdgcn_mfma_f32_16x16x32_bf16(valo[1], bh1, a1, 0, 0, 0);
        a0 = __builtin_amdgcn_mfma_f32_16x16x32_bf16(valo[0], bl0, a0, 0, 0, 0);
        a1 = __builtin_amdgcn_mfma_f32_16x16x32_bf16(valo[1], bl1, a1, 0, 0, 0);
        const float eps = e2s[t2 * 16 + cq];
        const int n = t2 * 16 + cq;
        #pragma unroll
        for (int r = 0; r < 4; ++r) {
            float d = fmaf(-2.f, a0[r] + a1[r], z2r[r] + eps);
            if (d < m1[r])      { m2[r] = m1[r]; m1[r] = d; i1[r] = n; }
            else if (d < m2[r]) { m2[r] = d; }
        }
    }

    // merge top-2 across the 16 columns of each lane group
    #pragma unroll
    for (int r = 0; r < 4; ++r) {
        #pragma unroll
        for (int off = 1; off <= 8; off <<= 1) {
            float o1 = __shfl_xor(m1[r], off, 64);
            float o2 = __shfl_xor(m2[r], off, 64);
            int   oi = __shfl_xor(i1[r], off, 64);
            if (o1 < m1[r] || (o1 == m1[r] && oi < i1[r])) {
                m2[r] = fminf(m1[r], o2); m1[r] = o1; i1[r] = oi;
            } else {
                m2[r] = fminf(m2[r], o1);
            }
        }
    }
    if (cq == 0) {
        #pragma unroll
        for (int r = 0; r < 4; ++r) {
            int tok = wvu * 16 + qd * 4 + r;
            dT[tok] = m1[r]; d2T[tok] = m2[r]; iT[tok] = i1[r];
        }
    }
    __syncthreads();

    if (wv == 0) {
        float mm1 = dT[lane], mm2 = d2T[lane];
        if (mm2 - mm1 < MARGIN) {               // near-tie -> fp64 refine
            int pos = atomicAdd(cnt, 1);
            if (pos < CAP) wl[pos] = ((b << 6) + lane) * 64 + h;
        }
        float ms = mm1;
        #pragma unroll
        for (int off = 32; off; off >>= 1) ms += __shfl_xor(ms, off, 64);
        if (lane == 0) atomicAdd(accs + 0, ms);
    }
    __syncthreads();

    // z_q write: wave wv writes channels [wv*16,(wv+1)*16); batched gather
    float* zrow = zq + ((size_t)(b * 64) << 12) + (h << 6) + lane;
    #pragma unroll
    for (int cc = 0; cc < 16; ++cc) {
        int c = wvu * 16 + cc;
        int id = iT[c];
        zrow[(size_t)c << 12] = emb[(id << 6) + lane];
    }
}

// ============================================================
// K4: fp64 refinement (blocks 0..255, persistent) + finalize (block 256)
// ============================================================
__global__ __launch_bounds__(256) void refine_fin(
    const float* __restrict__ x,
    const double* __restrict__ Wd,
    const double* __restrict__ bpd,
    const float* __restrict__ emb,
    const float* __restrict__ eft,
    const int* __restrict__ cnt, const int* __restrict__ wl,
    float* __restrict__ zq,
    const float* __restrict__ accs, const float* __restrict__ en,
    const float* __restrict__ r, float* __restrict__ out)
{
    const int tid = threadIdx.x, lane = tid & 63, wv = tid >> 6;

    if (blockIdx.x == 256) {
        if (wv == 0) {
            float hs = 0.f, rs = 0.f;
            #pragma unroll
            for (int jj = 0; jj < 8; ++jj) {
                int n = (jj << 6) + lane;
                float rv = r[n];
                float d = rv - en[n];
                hs = fmaf(d, d, hs);
                rs += fminf(fmaxf(rv, 0.9f), 1.1f);
            }
            #pragma unroll
            for (int off = 32; off; off >>= 1) { hs += __shfl_xor(hs, off, 64); rs += __shfl_xor(rs, off, 64); }
            if (lane == 0) {
                float hsw    = hs * (1.f / 512.f);
                float mean_r = rs * (1.f / 512.f);
                float mse    = accs[0] * (1.f / 4194304.f);
                float cbv    = accs[1] * (1.f / 512.f);
                float tmd    = accs[2] * (1.f / 512.f);
                float loss   = 2.f * mse + hsw + (cbv - tmd);
                out[0]       = loss;
                out[4194305] = cbv;
                out[4194306] = tmd;
                out[4194307] = hsw;
                out[4194308] = 0.f;
                out[4194309] = mean_r;
            }
        }
        return;
    }

    int count = cnt[0]; if (count > CAP) count = CAP;

    __shared__ double zp[4][64];
    __shared__ double zs[64];
    __shared__ double dsh[256];
    __shared__ int    ish[256];

    for (int it = blockIdx.x; it < count; it += 256) {
        const int r2 = wl[it];
        const int b = r2 >> 12, c = (r2 >> 6) & 63, h = r2 & 63;

        const float* xp = x + (((size_t)(b * 256 + wv * 64)) << 12) + (h << 6) + lane;
        const double* wrow = Wd + c * 256 + wv * 64;
        double zd = 0.0;
        #pragma unroll 8
        for (int f = 0; f < 64; ++f)
            zd = fma(wrow[f], (double)xp[((size_t)f) << 12], zd);
        zp[wv][lane] = zd;
        __syncthreads();
        if (tid < 64) zs[tid] = (zp[0][tid] + zp[1][tid]) + (zp[2][tid] + zp[3][tid]) + bpd[c];
        __syncthreads();

        double dm = 1e300; int im = 0;
        #pragma unroll
        for (int jj = 0; jj < 2; ++jj) {
            int n = (jj << 8) + tid;
            double d = 0.0;
            #pragma unroll 8
            for (int k = 0; k < 64; ++k) {
                double t = zs[k] - (double)eft[(k << 9) + n];
                d = fma(t, t, d);
            }
            if (d < dm) { dm = d; im = n; }
        }
        dsh[tid] = dm; ish[tid] = im;
        __syncthreads();
        for (int st = 128; st; st >>= 1) {
            if (tid < st) {
                double od = dsh[tid + st]; int oi = ish[tid + st];
                if (od < dsh[tid] || (od == dsh[tid] && oi < ish[tid])) { dsh[tid] = od; ish[tid] = oi; }
            }
            __syncthreads();
        }
        if (tid < 64) {
            int idx = ish[0];
            zq[((size_t)r2 << 6) + tid] = emb[(idx << 6) + tid];
        }
        __syncthreads();
    }
}

// ============================================================
extern "C" void kernel_launch(void* const* d_in, const int* in_sizes, int n_in,
                              void* d_out, int out_size, void* d_ws, size_t ws_size,
                              hipStream_t stream) {
    const float* x   = (const float*)d_in[0];
    const float* g1  = (const float*)d_in[1];
    const float* be1 = (const float*)d_in[2];
    const float* w1  = (const float*)d_in[3];
    const float* b1  = (const float*)d_in[4];
    const float* w2  = (const float*)d_in[5];
    const float* b2  = (const float*)d_in[6];
    const float* emb = (const float*)d_in[7];
    const float* r   = (const float*)d_in[8];
    float* ws = (float*)d_ws;
    float* out = (float*)d_out;

    double* WD   = (double*)(ws + WS_WD);
    double* BPD  = (double*)(ws + WS_BPD);
    double* PART = (double*)(ws + WS_PART);
    int*    CNT  = (int*)(ws + WS_CNT);
    int*    WL   = (int*)(ws + WS_WL);
    unsigned short* WHI = (unsigned short*)(ws + WS_WHI);
    unsigned short* WLO = (unsigned short*)(ws + WS_WLO);
    unsigned short* EHI = (unsigned short*)(ws + WS_EHI);
    unsigned short* ELO = (unsigned short*)(ws + WS_ELO);

    bn_partial<<<512, 256, 0, stream>>>(x, PART);
    prep<<<65, 256, 0, stream>>>(w1, w2, b1, b2, g1, be1, emb, PART,
                                 WHI, WLO, WD, BPD, ws + WS_BP,
                                 ws + WS_EFT, ws + WS_EN, ws + WS_E2,
                                 EHI, ELO, ws + WS_ACC, CNT);
    fused_gemm_vq<<<1536, 256, 0, stream>>>(x, WHI, WLO, ws + WS_BP,
                                            emb, ws + WS_E2, ws + WS_EN, ws + WS_EFT,
                                            EHI, ELO, ws + WS_ACC, CNT, WL, out + 1);
    refine_fin<<<257, 256, 0, stream>>>(x, WD, BPD, emb, ws + WS_EFT, CNT, WL,
                                        out + 1, ws + WS_ACC, ws + WS_EN, r, out);
}